// Round 16
// baseline (244.261 us; speedup 1.0000x reference)
//
#include <hip/hip_runtime.h>
#include <cmath>

#define NB 32
#define NN 1024
#define NC 64
#define NE 16

typedef _Float16 f16;
typedef __attribute__((ext_vector_type(2))) _Float16 f16x2;
typedef __attribute__((ext_vector_type(4))) _Float16 f16x4;
typedef __attribute__((ext_vector_type(8))) _Float16 f16x8;
typedef __attribute__((ext_vector_type(16))) float f32x16;

#define NVSTR 24
#define SSTR  40
#define XSTR  40
#define ASTR  40
#define A5STR 72

__device__ __forceinline__ float sigm(float v) { return 1.0f / (1.0f + expf(-v)); }
__device__ __forceinline__ float lrelu(float v) { return v > 0.0f ? v : 0.01f * v; }

// ---------------- nv body (one thread per row) as device function ----------------
__device__ __forceinline__ void nv_row(
    int row,
    const float* __restrict__ x, const float* __restrict__ emb0,
    const float* __restrict__ speed, const float* __restrict__ occupy,
    const float* __restrict__ fw1, const float* __restrict__ fb1,
    const float* __restrict__ fw2, const float* __restrict__ fb2,
    const float* __restrict__ fw3, const float* __restrict__ fb3,
    const float* __restrict__ gw1, const float* __restrict__ gb1,
    const float* __restrict__ gw2, const float* __restrict__ gb2,
    const float* __restrict__ gw3, const float* __restrict__ gb3,
    float* __restrict__ nv_out)
{
    float h1[16];
    #pragma unroll
    for (int j = 0; j < 16; ++j) h1[j] = fb1[j];
    {
        const float4* xr = reinterpret_cast<const float4*>(x + (size_t)row * 64);
        #pragma unroll
        for (int i4 = 0; i4 < 16; ++i4) {
            float4 xv = xr[i4];
            #pragma unroll
            for (int j = 0; j < 16; ++j) {
                const float* wr = fw1 + j * 64 + i4 * 4;
                h1[j] += xv.x * wr[0] + xv.y * wr[1] + xv.z * wr[2] + xv.w * wr[3];
            }
        }
    }
    #pragma unroll
    for (int j = 0; j < 16; ++j) h1[j] = sigm(h1[j]);

    float h2a = fb2[0], h2b = fb2[1];
    #pragma unroll
    for (int j = 0; j < 16; ++j) { h2a += h1[j] * fw2[j]; h2b += h1[j] * fw2[16 + j]; }
    h2a = sigm(h2a); h2b = sigm(h2b);

    const float sp = speed[row], oc = occupy[row];
    float ga = gb2[0], gb_ = gb2[1];
    float oa = gb2[0], ob_ = gb2[1];
    #pragma unroll
    for (int j = 0; j < 16; ++j) {
        float g1 = sigm(sp * gw1[j] + gb1[j]);
        float o1 = sigm(oc * gw1[j] + gb1[j]);
        ga += g1 * gw2[j];  gb_ += g1 * gw2[16 + j];
        oa += o1 * gw2[j];  ob_ += o1 * gw2[16 + j];
    }
    ga = sigm(ga); gb_ = sigm(gb_); oa = sigm(oa); ob_ = sigm(ob_);

    const float* e0 = emb0 + (size_t)row * 16;
    float vout[16];
    #pragma unroll
    for (int j = 0; j < 16; ++j) {
        float filt = h2a * fw3[j * 2] + h2b * fw3[j * 2 + 1] + fb3[j];
        float f1v  = ga  * gw3[j * 2] + gb_ * gw3[j * 2 + 1] + gb3[j];
        float f2v  = oa  * gw3[j * 2] + ob_ * gw3[j * 2 + 1] + gb3[j];
        float v = tanhf(e0[j] * filt);
        v = tanhf(v * f1v);
        v = tanhf(v * f2v);
        vout[j] = v;
    }
    float4* dst = reinterpret_cast<float4*>(nv_out + (size_t)row * 16);
    #pragma unroll
    for (int q = 0; q < 4; ++q) {
        float4 o; o.x = vout[4 * q]; o.y = vout[4 * q + 1]; o.z = vout[4 * q + 2]; o.w = vout[4 * q + 3];
        dst[q] = o;
    }
}

// ---------------- Fallback nv kernel (mid/low tiers) ----------------
__global__ __launch_bounds__(64) void nv_kernel(
    const float* __restrict__ x, const float* __restrict__ emb0,
    const float* __restrict__ speed, const float* __restrict__ occupy,
    const float* __restrict__ fw1, const float* __restrict__ fb1,
    const float* __restrict__ fw2, const float* __restrict__ fb2,
    const float* __restrict__ fw3, const float* __restrict__ fb3,
    const float* __restrict__ gw1, const float* __restrict__ gb1,
    const float* __restrict__ gw2, const float* __restrict__ gb2,
    const float* __restrict__ gw3, const float* __restrict__ gb3,
    float* __restrict__ nv_out)
{
    nv_row(blockIdx.x * 64 + threadIdx.x, x, emb0, speed, occupy,
           fw1, fb1, fw2, fb2, fw3, fb3, gw1, gb1, gw2, gb2, gw3, gb3, nv_out);
}

// ---------------- nvxsplit: fused nv + x transpose/split (one launch) ----------------
__global__ __launch_bounds__(256) void nvxsplit_kernel(
    const float* __restrict__ x, const float* __restrict__ emb0,
    const float* __restrict__ speed, const float* __restrict__ occupy,
    const float* __restrict__ fw1, const float* __restrict__ fb1,
    const float* __restrict__ fw2, const float* __restrict__ fb2,
    const float* __restrict__ fw3, const float* __restrict__ fb3,
    const float* __restrict__ gw1, const float* __restrict__ gb1,
    const float* __restrict__ gw2, const float* __restrict__ gb2,
    const float* __restrict__ gw3, const float* __restrict__ gb3,
    float* __restrict__ nv_out, f16* __restrict__ Th, f16* __restrict__ Tl)
{
    __shared__ float tile[64][65];
    const int t = threadIdx.x;

    if ((int)blockIdx.x < NB * 16) {
        const int b = blockIdx.x >> 4;
        const int n0 = (blockIdx.x & 15) * 64;
        {
            int r = t >> 2;
            const float4* src = reinterpret_cast<const float4*>(x + ((size_t)b * NN + n0 + r) * NC);
            #pragma unroll
            for (int i = 0; i < 4; ++i) {
                int fi = (t & 3) + 4 * i;
                float4 vv = src[fi];
                tile[r][fi * 4 + 0] = vv.x; tile[r][fi * 4 + 1] = vv.y;
                tile[r][fi * 4 + 2] = vv.z; tile[r][fi * 4 + 3] = vv.w;
            }
        }
        __syncthreads();
        const int c = t & 63, ng = (t >> 6) * 16;
        f16x8 ph0, ph1, pl0, pl1;
        #pragma unroll
        for (int j = 0; j < 8; ++j) {
            float v = tile[ng + j][c];
            f16 h = (f16)v; ph0[j] = h; pl0[j] = (f16)(v - (float)h);
        }
        #pragma unroll
        for (int j = 0; j < 8; ++j) {
            float v = tile[ng + 8 + j][c];
            f16 h = (f16)v; ph1[j] = h; pl1[j] = (f16)(v - (float)h);
        }
        f16* dh = Th + ((size_t)b * NC + c) * NN + n0 + ng;
        f16* dl = Tl + ((size_t)b * NC + c) * NN + n0 + ng;
        *(f16x8*)dh = ph0; *(f16x8*)(dh + 8) = ph1;
        *(f16x8*)dl = pl0; *(f16x8*)(dl + 8) = pl1;
    } else {
        const int row = ((int)blockIdx.x - NB * 16) * 256 + t;
        nv_row(row, x, emb0, speed, occupy,
               fw1, fb1, fw2, fb2, fw3, fb3, gw1, gb1, gw2, gb2, gw3, gb3, nv_out);
    }
}

// ------- sgen_fused: S = relu(nv nv^T) materialized AND step-1 y = lrelu(S x) in one pass -------
__global__ __launch_bounds__(512, 2) void sgen_fused_kernel(
    const float* __restrict__ nv,
    const f16* __restrict__ xTh, const f16* __restrict__ xTl,
    f16* __restrict__ Sh, f16* __restrict__ Sl,
    float* __restrict__ yout, f16* __restrict__ yTh, f16* __restrict__ yTl)
{
    const int b = blockIdx.x;
    const int m0 = blockIdx.y * 128;
    const int t = threadIdx.x;
    const int l = t & 63;
    const int g = l >> 5;
    const int l31 = l & 31;
    const int w = t >> 6;
    const int mq = w >> 1;
    const int nh = w & 1;

    __shared__ __align__(16) f16 nvBh[128 * NVSTR], nvBl[128 * NVSTR];
    __shared__ __align__(16) f16 Xsh[4][64 * XSTR], Xsl[4][64 * XSTR];
    __shared__ __align__(16) f16 Sth[4][128 * SSTR], Stl[4][128 * SSTR];

    const size_t sbase = (size_t)b * NN * NN;

    {
        int row = t >> 2, e0 = (t & 3) * 4;
        const float* src = nv + ((size_t)b * NN + m0 + row) * NE + e0;
        float v0 = src[0], v1 = src[1], v2 = src[2], v3 = src[3];
        f16x4 ph, pl;
        ph[0] = (f16)v0; pl[0] = (f16)(v0 - (float)ph[0]);
        ph[1] = (f16)v1; pl[1] = (f16)(v1 - (float)ph[1]);
        ph[2] = (f16)v2; pl[2] = (f16)(v2 - (float)ph[2]);
        ph[3] = (f16)v3; pl[3] = (f16)(v3 - (float)ph[3]);
        *(f16x4*)&Sth[0][row * NVSTR + e0] = ph;
        *(f16x4*)&Stl[0][row * NVSTR + e0] = pl;
    }
    __syncthreads();
    f16x8 Ah = *(const f16x8*)&Sth[0][(mq * 32 + l31) * NVSTR + g * 8];
    f16x8 Al = *(const f16x8*)&Stl[0][(mq * 32 + l31) * NVSTR + g * 8];

    f32x16 acc0, acc1;
    #pragma unroll
    for (int r = 0; r < 16; ++r) { acc0[r] = 0.0f; acc1[r] = 0.0f; }

    const int brow = t >> 2, be0 = (t & 3) * 4;
    const int xc = t >> 3, xpart = t & 7;
    const int xsub = xpart >> 1, xhalf = xpart & 1;

    for (int it = 0; it < 8; ++it) {
        {
            const float* src = nv + ((size_t)b * NN + it * 128 + brow) * NE + be0;
            float v0 = src[0], v1 = src[1], v2 = src[2], v3 = src[3];
            f16x4 ph, pl;
            ph[0] = (f16)v0; pl[0] = (f16)(v0 - (float)ph[0]);
            ph[1] = (f16)v1; pl[1] = (f16)(v1 - (float)ph[1]);
            ph[2] = (f16)v2; pl[2] = (f16)(v2 - (float)ph[2]);
            ph[3] = (f16)v3; pl[3] = (f16)(v3 - (float)ph[3]);
            *(f16x4*)&nvBh[brow * NVSTR + be0] = ph;
            *(f16x4*)&nvBl[brow * NVSTR + be0] = pl;
        }
        {
            const f16* sH = xTh + ((size_t)b * NC + xc) * NN + it * 128 + xsub * 32 + xhalf * 16;
            const f16* sL = xTl + ((size_t)b * NC + xc) * NN + it * 128 + xsub * 32 + xhalf * 16;
            *(f16x8*)&Xsh[xsub][xc * XSTR + xhalf * 16] = *(const f16x8*)sH;
            *(f16x8*)&Xsh[xsub][xc * XSTR + xhalf * 16 + 8] = *(const f16x8*)(sH + 8);
            *(f16x8*)&Xsl[xsub][xc * XSTR + xhalf * 16] = *(const f16x8*)sL;
            *(f16x8*)&Xsl[xsub][xc * XSTR + xhalf * 16 + 8] = *(const f16x8*)(sL + 8);
        }
        __syncthreads();

        #pragma unroll
        for (int tl = 0; tl < 2; ++tl) {
            const int tile = nh * 2 + tl;
            f16x8 Bh = *(const f16x8*)&nvBh[(tile * 32 + l31) * NVSTR + g * 8];
            f16x8 Bl = *(const f16x8*)&nvBl[(tile * 32 + l31) * NVSTR + g * 8];
            f32x16 sa;
            #pragma unroll
            for (int r = 0; r < 16; ++r) sa[r] = 0.0f;
            sa = __builtin_amdgcn_mfma_f32_32x32x16_f16(Al, Bh, sa, 0, 0, 0);
            sa = __builtin_amdgcn_mfma_f32_32x32x16_f16(Ah, Bl, sa, 0, 0, 0);
            sa = __builtin_amdgcn_mfma_f32_32x32x16_f16(Ah, Bh, sa, 0, 0, 0);
            const int n = it * 128 + tile * 32 + l31;
            #pragma unroll
            for (int r = 0; r < 16; ++r) {
                float vv = fmaxf(sa[r], 0.0f);
                f16 h = (f16)vv; f16 lo = (f16)(vv - (float)h);
                int mloc = mq * 32 + (r & 3) + 8 * (r >> 2) + 4 * g;
                Sh[sbase + (size_t)(m0 + mloc) * NN + n] = h;
                Sl[sbase + (size_t)(m0 + mloc) * NN + n] = lo;
                Sth[tile][mloc * SSTR + l31] = h;
                Stl[tile][mloc * SSTR + l31] = lo;
            }
        }
        __syncthreads();

        #pragma unroll
        for (int tl = 0; tl < 2; ++tl) {
            const int tile = nh * 2 + tl;
            #pragma unroll
            for (int ku = 0; ku < 2; ++ku) {
                f16x8 Ah2 = *(const f16x8*)&Sth[tile][(mq * 32 + l31) * SSTR + ku * 16 + g * 8];
                f16x8 Al2 = *(const f16x8*)&Stl[tile][(mq * 32 + l31) * SSTR + ku * 16 + g * 8];
                {
                    f16x8 Bh = *(const f16x8*)&Xsh[tile][l31 * XSTR + ku * 16 + g * 8];
                    f16x8 Bl = *(const f16x8*)&Xsl[tile][l31 * XSTR + ku * 16 + g * 8];
                    acc0 = __builtin_amdgcn_mfma_f32_32x32x16_f16(Al2, Bh, acc0, 0, 0, 0);
                    acc0 = __builtin_amdgcn_mfma_f32_32x32x16_f16(Ah2, Bl, acc0, 0, 0, 0);
                    acc0 = __builtin_amdgcn_mfma_f32_32x32x16_f16(Ah2, Bh, acc0, 0, 0, 0);
                }
                {
                    f16x8 Bh = *(const f16x8*)&Xsh[tile][(32 + l31) * XSTR + ku * 16 + g * 8];
                    f16x8 Bl = *(const f16x8*)&Xsl[tile][(32 + l31) * XSTR + ku * 16 + g * 8];
                    acc1 = __builtin_amdgcn_mfma_f32_32x32x16_f16(Al2, Bh, acc1, 0, 0, 0);
                    acc1 = __builtin_amdgcn_mfma_f32_32x32x16_f16(Ah2, Bl, acc1, 0, 0, 0);
                    acc1 = __builtin_amdgcn_mfma_f32_32x32x16_f16(Ah2, Bh, acc1, 0, 0, 0);
                }
            }
        }
        __syncthreads();
    }

    float* red = reinterpret_cast<float*>(&Sth[0][0]);
    if (nh == 1) {
        #pragma unroll
        for (int r = 0; r < 16; ++r) {
            int crow = (r & 3) + 8 * (r >> 2) + 4 * g;
            red[((mq * 2 + 0) * 32 + crow) * 33 + l31] = acc0[r];
            red[((mq * 2 + 1) * 32 + crow) * 33 + l31] = acc1[r];
        }
    }
    __syncthreads();
    if (nh == 0) {
        #pragma unroll
        for (int ch = 0; ch < 2; ++ch) {
            const int colg = ch * 32 + l31;
            #pragma unroll
            for (int q = 0; q < 4; ++q) {
                float v[4];
                #pragma unroll
                for (int j = 0; j < 4; ++j) {
                    int r = q * 4 + j;
                    int crow = j + 8 * q + 4 * g;
                    float part = (ch == 0) ? acc0[r] : acc1[r];
                    v[j] = lrelu(part + red[((mq * 2 + ch) * 32 + crow) * 33 + l31]);
                }
                const int mrow = m0 + mq * 32 + 8 * q + 4 * g;
                #pragma unroll
                for (int j = 0; j < 4; ++j)
                    yout[((size_t)b * NN + mrow + j) * NC + colg] = v[j];
                f16x4 ph, pl;
                #pragma unroll
                for (int j = 0; j < 4; ++j) {
                    f16 h = (f16)v[j];
                    ph[j] = h; pl[j] = (f16)(v[j] - (float)h);
                }
                *(f16x4*)&yTh[((size_t)b * NC + colg) * NN + mrow] = ph;
                *(f16x4*)&yTl[((size_t)b * NC + colg) * NN + mrow] = pl;
            }
        }
    }
}

// ------- diffuse5: y = lrelu(S x); M=64, 4 waves (mh,ch), pure-b128 staging from planes -------
__global__ __launch_bounds__(256) void diffuse5_kernel(
    const f16* __restrict__ Sh, const f16* __restrict__ Sl,
    const f16* __restrict__ xTh, const f16* __restrict__ xTl,
    float* __restrict__ yout, f16* __restrict__ yTh, f16* __restrict__ yTl,
    int writeT)
{
    const int b = blockIdx.x;
    const int m0 = blockIdx.y * 64;
    const int t = threadIdx.x;
    const int l = t & 63;
    const int g = l >> 5;
    const int l31 = l & 31;
    const int w = t >> 6;
    const int mh = w & 1;
    const int ch = w >> 1;

    __shared__ __align__(16) f16 As_h[2][64 * ASTR], As_l[2][64 * ASTR];
    __shared__ __align__(16) f16 Xs_h[2][64 * XSTR], Xs_l[2][64 * XSTR];

    const int arow = t >> 2, akc = t & 3;
    const f16* Ah_src = Sh + (size_t)b * NN * NN + (size_t)(m0 + arow) * NN + akc * 8;
    const f16* Al_src = Sl + (size_t)b * NN * NN + (size_t)(m0 + arow) * NN + akc * 8;
    const f16* Xh_src = xTh + ((size_t)b * NC + arow) * NN + akc * 8;
    const f16* Xl_src = xTl + ((size_t)b * NC + arow) * NN + akc * 8;

#define D5STAGE(n0v, bufv) do { \
    *(f16x8*)&As_h[bufv][arow * ASTR + akc * 8] = *(const f16x8*)(Ah_src + (n0v)); \
    *(f16x8*)&As_l[bufv][arow * ASTR + akc * 8] = *(const f16x8*)(Al_src + (n0v)); \
    *(f16x8*)&Xs_h[bufv][arow * XSTR + akc * 8] = *(const f16x8*)(Xh_src + (n0v)); \
    *(f16x8*)&Xs_l[bufv][arow * XSTR + akc * 8] = *(const f16x8*)(Xl_src + (n0v)); \
} while (0)

#define D5MFMA(bufv) do { \
    _Pragma("unroll") \
    for (int ku = 0; ku < 2; ++ku) { \
        f16x8 Bh = *(const f16x8*)&Xs_h[bufv][(ch * 32 + l31) * XSTR + ku * 16 + g * 8]; \
        f16x8 Bl = *(const f16x8*)&Xs_l[bufv][(ch * 32 + l31) * XSTR + ku * 16 + g * 8]; \
        f16x8 Ah = *(const f16x8*)&As_h[bufv][(mh * 32 + l31) * ASTR + ku * 16 + g * 8]; \
        f16x8 Al = *(const f16x8*)&As_l[bufv][(mh * 32 + l31) * ASTR + ku * 16 + g * 8]; \
        acc = __builtin_amdgcn_mfma_f32_32x32x16_f16(Al, Bh, acc, 0, 0, 0); \
        acc = __builtin_amdgcn_mfma_f32_32x32x16_f16(Ah, Bl, acc, 0, 0, 0); \
        acc = __builtin_amdgcn_mfma_f32_32x32x16_f16(Ah, Bh, acc, 0, 0, 0); \
    } \
} while (0)

    f32x16 acc;
    #pragma unroll
    for (int r = 0; r < 16; ++r) acc[r] = 0.0f;

    D5STAGE(0, 0);
    __syncthreads();

    for (int s = 0; s < 32; ++s) {
        const int cur = s & 1;
        if (s + 1 < 32) D5STAGE((s + 1) * 32, cur ^ 1);
        D5MFMA(cur);
        __syncthreads();
    }
#undef D5STAGE
#undef D5MFMA

    const int colg = ch * 32 + l31;
    #pragma unroll
    for (int q = 0; q < 4; ++q) {
        float v[4];
        #pragma unroll
        for (int j = 0; j < 4; ++j) {
            int r = q * 4 + j;
            v[j] = lrelu(acc[r]);
        }
        const int mrow = m0 + mh * 32 + 8 * q + 4 * g;
        #pragma unroll
        for (int j = 0; j < 4; ++j)
            yout[((size_t)b * NN + mrow + j) * NC + colg] = v[j];
        if (writeT) {
            f16x4 ph, pl;
            #pragma unroll
            for (int j = 0; j < 4; ++j) {
                f16 h = (f16)v[j];
                ph[j] = h; pl[j] = (f16)(v[j] - (float)h);
            }
            *(f16x4*)&yTh[((size_t)b * NC + colg) * NN + mrow] = ph;
            *(f16x4*)&yTl[((size_t)b * NC + colg) * NN + mrow] = pl;
        }
    }
}

// ------- Fallback (fused MFMA diffuse, r4) -------
__global__ __launch_bounds__(256) void diffuse_mfma_kernel(
    const float* __restrict__ nv, const float* __restrict__ xin,
    float* __restrict__ yout)
{
    const int b = blockIdx.x;
    const int m0 = blockIdx.y * 128;
    const int t = threadIdx.x;
    const int l = t & 63;
    const int w = t >> 6;
    const int g = l >> 5;
    const int l31 = l & 31;

    __shared__ __align__(16) f16 nvA_h[128 * NVSTR], nvA_l[128 * NVSTR];
    __shared__ __align__(16) f16 nvB_h[2][32 * NVSTR], nvB_l[2][32 * NVSTR];
    __shared__ __align__(16) f16 xT_h[2][64 * XSTR], xT_l[2][64 * XSTR];
    __shared__ __align__(16) f16 S_h[128 * SSTR], S_l[128 * SSTR];

    {
        int row = t >> 1, e0 = (t & 1) * 8;
        const float* src = nv + ((size_t)b * NN + m0 + row) * NE + e0;
        #pragma unroll
        for (int q = 0; q < 4; ++q) {
            float v0 = src[2 * q], v1 = src[2 * q + 1];
            f16 h0 = (f16)v0, h1 = (f16)v1;
            f16 lo0 = (f16)(v0 - (float)h0), lo1 = (f16)(v1 - (float)h1);
            f16x2 ph; ph[0] = h0; ph[1] = h1;
            f16x2 pl; pl[0] = lo0; pl[1] = lo1;
            *(f16x2*)&nvA_h[row * NVSTR + e0 + 2 * q] = ph;
            *(f16x2*)&nvA_l[row * NVSTR + e0 + 2 * q] = pl;
        }
    }

#define STAGE(n0v, bufv) do { \
    if (t < 64) { \
        int nl_ = t >> 1, e0_ = (t & 1) * 8; \
        const float* s_ = nv + ((size_t)b * NN + (n0v) + nl_) * NE + e0_; \
        _Pragma("unroll") \
        for (int q = 0; q < 4; ++q) { \
            float v0 = s_[2 * q], v1 = s_[2 * q + 1]; \
            f16 h0 = (f16)v0, h1 = (f16)v1; \
            f16 lo0 = (f16)(v0 - (float)h0), lo1 = (f16)(v1 - (float)h1); \
            f16x2 ph; ph[0] = h0; ph[1] = h1; \
            f16x2 pl; pl[0] = lo0; pl[1] = lo1; \
            *(f16x2*)&nvB_h[bufv][nl_ * NVSTR + e0_ + 2 * q] = ph; \
            *(f16x2*)&nvB_l[bufv][nl_ * NVSTR + e0_ + 2 * q] = pl; \
        } \
    } \
    { \
        int k_ = t >> 3, c0_ = t & 7; \
        const float* s_ = xin + ((size_t)b * NN + (n0v) + k_) * NC + c0_; \
        _Pragma("unroll") \
        for (int i = 0; i < 8; ++i) { \
            float v = s_[8 * i]; \
            f16 h = (f16)v; f16 lo = (f16)(v - (float)h); \
            int c_ = c0_ + 8 * i; \
            xT_h[bufv][c_ * XSTR + k_] = h; \
            xT_l[bufv][c_ * XSTR + k_] = lo; \
        } \
    } \
} while (0)

    STAGE(0, 0);
    __syncthreads();

    f32x16 acc0, acc1;
    #pragma unroll
    for (int r = 0; r < 16; ++r) { acc0[r] = 0.0f; acc1[r] = 0.0f; }

    const int mh = w & 1;
    const int cc = w >> 1;

    for (int s = 0; s < 32; ++s) {
        const int cur = s & 1;
        {
            f16x8 Ah = *(const f16x8*)&nvA_h[(w * 32 + l31) * NVSTR + g * 8];
            f16x8 Al = *(const f16x8*)&nvA_l[(w * 32 + l31) * NVSTR + g * 8];
            f16x8 Bh = *(const f16x8*)&nvB_h[cur][l31 * NVSTR + g * 8];
            f16x8 Bl = *(const f16x8*)&nvB_l[cur][l31 * NVSTR + g * 8];
            f32x16 sa;
            #pragma unroll
            for (int r = 0; r < 16; ++r) sa[r] = 0.0f;
            sa = __builtin_amdgcn_mfma_f32_32x32x16_f16(Al, Bh, sa, 0, 0, 0);
            sa = __builtin_amdgcn_mfma_f32_32x32x16_f16(Ah, Bl, sa, 0, 0, 0);
            sa = __builtin_amdgcn_mfma_f32_32x32x16_f16(Ah, Bh, sa, 0, 0, 0);
            #pragma unroll
            for (int r = 0; r < 16; ++r) {
                float vv = fmaxf(sa[r], 0.0f);
                f16 h = (f16)vv; f16 lo = (f16)(vv - (float)h);
                int row = w * 32 + (r & 3) + 8 * (r >> 2) + 4 * g;
                S_h[row * SSTR + l31] = h;
                S_l[row * SSTR + l31] = lo;
            }
        }
        if (s + 1 < 32) STAGE((s + 1) * 32, cur ^ 1);
        __syncthreads();
        #pragma unroll
        for (int chh = 0; chh < 2; ++chh) {
            f16x8 Bh = *(const f16x8*)&xT_h[cur][(cc * 32 + l31) * XSTR + chh * 16 + g * 8];
            f16x8 Bl = *(const f16x8*)&xT_l[cur][(cc * 32 + l31) * XSTR + chh * 16 + g * 8];
            {
                int sr = (mh * 64 + l31) * SSTR + chh * 16 + g * 8;
                f16x8 Ah = *(const f16x8*)&S_h[sr];
                f16x8 Al = *(const f16x8*)&S_l[sr];
                acc0 = __builtin_amdgcn_mfma_f32_32x32x16_f16(Al, Bh, acc0, 0, 0, 0);
                acc0 = __builtin_amdgcn_mfma_f32_32x32x16_f16(Ah, Bl, acc0, 0, 0, 0);
                acc0 = __builtin_amdgcn_mfma_f32_32x32x16_f16(Ah, Bh, acc0, 0, 0, 0);
            }
            {
                int sr = (mh * 64 + 32 + l31) * SSTR + chh * 16 + g * 8;
                f16x8 Ah = *(const f16x8*)&S_h[sr];
                f16x8 Al = *(const f16x8*)&S_l[sr];
                acc1 = __builtin_amdgcn_mfma_f32_32x32x16_f16(Al, Bh, acc1, 0, 0, 0);
                acc1 = __builtin_amdgcn_mfma_f32_32x32x16_f16(Ah, Bl, acc1, 0, 0, 0);
                acc1 = __builtin_amdgcn_mfma_f32_32x32x16_f16(Ah, Bh, acc1, 0, 0, 0);
            }
        }
        __syncthreads();
    }
#undef STAGE

    const int colg = cc * 32 + l31;
    #pragma unroll
    for (int r = 0; r < 16; ++r) {
        int row0 = m0 + mh * 64 + (r & 3) + 8 * (r >> 2) + 4 * g;
        yout[((size_t)b * NN + row0) * NC + colg] = lrelu(acc0[r]);
        yout[((size_t)b * NN + row0 + 32) * NC + colg] = lrelu(acc1[r]);
    }
}

// ======= Attention pool, stage A: per-row scores (one wave per row) =======
__global__ __launch_bounds__(256) void scores_kernel(
    const float* __restrict__ x, const float* __restrict__ xs1, const float* __restrict__ xs2,
    const float* __restrict__ xb1, const float* __restrict__ xb2,
    const float* __restrict__ att_w, const float* __restrict__ att_b,
    float* __restrict__ sc)
{
    const int lane = threadIdx.x & 63;
    const int w = threadIdx.x >> 6;
    const int r = blockIdx.x * 4 + w;
    const int which = r >= NB * NN;
    const int rr = r - which * NB * NN;

    const float* p0 = which ? xs2 : x;
    const float* p1 = which ? xb1 : xs1;
    const float* p2 = which ? xb2 : xs2;

    size_t idx = (size_t)rr * NC + lane;
    float nf = (p0[idx] + p1[idx] + p2[idx]) * (1.0f / 3.0f);
    float v = nf * att_w[lane];
    #pragma unroll
    for (int off = 32; off > 0; off >>= 1) v += __shfl_xor(v, off);
    if (lane == 0) sc[r] = v + att_b[0];
}

// ======= Fallback softmax (mid tier) =======
__global__ __launch_bounds__(256) void softmax_kernel(float* __restrict__ sc)
{
    const int wb = blockIdx.x;
    const int t = threadIdx.x;
    const int lane = t & 63;
    const int w = t >> 6;
    float* p = sc + (size_t)wb * NN;

    __shared__ float red[4];
    float4 v = reinterpret_cast<const float4*>(p)[t];
    float m = fmaxf(fmaxf(v.x, v.y), fmaxf(v.z, v.w));
    #pragma unroll
    for (int off = 32; off > 0; off >>= 1) m = fmaxf(m, __shfl_xor(m, off));
    if (lane == 0) red[w] = m;
    __syncthreads();
    m = fmaxf(fmaxf(red[0], red[1]), fmaxf(red[2], red[3]));
    __syncthreads();
    v.x = expf(v.x - m); v.y = expf(v.y - m); v.z = expf(v.z - m); v.w = expf(v.w - m);
    float s = v.x + v.y + v.z + v.w;
    #pragma unroll
    for (int off = 32; off > 0; off >>= 1) s += __shfl_xor(s, off);
    if (lane == 0) red[w] = s;
    __syncthreads();
    const float inv = 1.0f / (red[0] + red[1] + red[2] + red[3]);
    v.x *= inv; v.y *= inv; v.z *= inv; v.w *= inv;
    reinterpret_cast<float4*>(p)[t] = v;
}

// ======= poolpart2: inline softmax stats (scb stays RAW scores) + weighted partials =======
__global__ __launch_bounds__(256) void poolpart2_kernel(
    const float* __restrict__ x, const float* __restrict__ xs1, const float* __restrict__ xs2,
    const float* __restrict__ xb1, const float* __restrict__ xb2,
    const float* __restrict__ sc, float* __restrict__ partial)
{
    const int chunk = blockIdx.x;
    const int b = blockIdx.y;
    const int which = blockIdx.z;
    const int t = threadIdx.x;
    const int lane = t & 63;
    const int w = t >> 6;

    const float* p0 = which ? xs2 : x;
    const float* p1 = which ? xb1 : xs1;
    const float* p2 = which ? xb2 : xs2;
    const float* srow = sc + ((size_t)which * NB + b) * NN;

    __shared__ float redm[4];
    __shared__ float reds[4];
    __shared__ float red[4][64];

    float4 v = reinterpret_cast<const float4*>(srow)[t];
    float m = fmaxf(fmaxf(v.x, v.y), fmaxf(v.z, v.w));
    #pragma unroll
    for (int off = 32; off > 0; off >>= 1) m = fmaxf(m, __shfl_xor(m, off));
    if (lane == 0) redm[w] = m;
    __syncthreads();
    m = fmaxf(fmaxf(redm[0], redm[1]), fmaxf(redm[2], redm[3]));
    float s = expf(v.x - m) + expf(v.y - m) + expf(v.z - m) + expf(v.w - m);
    #pragma unroll
    for (int off = 32; off > 0; off >>= 1) s += __shfl_xor(s, off);
    if (lane == 0) reds[w] = s;
    __syncthreads();
    const float inv = 1.0f / (reds[0] + reds[1] + reds[2] + reds[3]);

    const int n0 = chunk * 64;
    const size_t base = (size_t)b * NN;
    float acc = 0.0f;
    for (int j = w; j < 64; j += 4) {
        int n = n0 + j;
        float wgt = expf(srow[n] - m) * inv;
        size_t idx = (base + n) * NC + lane;
        float nf = (p0[idx] + p1[idx] + p2[idx]) * (1.0f / 3.0f);
        acc += nf * wgt;
    }
    red[w][lane] = acc;
    __syncthreads();
    if (w == 0) {
        float sv = red[0][lane] + red[1][lane] + red[2][lane] + red[3][lane];
        partial[(((size_t)which * NB + b) * 16 + chunk) * 64 + lane] = sv;
    }
}

// ======= Fallback poolpart (mid tier, expects normalized sc) =======
__global__ __launch_bounds__(256) void poolpart_kernel(
    const float* __restrict__ x, const float* __restrict__ xs1, const float* __restrict__ xs2,
    const float* __restrict__ xb1, const float* __restrict__ xb2,
    const float* __restrict__ sc, float* __restrict__ partial)
{
    const int chunk = blockIdx.x;
    const int b = blockIdx.y;
    const int which = blockIdx.z;
    const int lane = threadIdx.x & 63;
    const int w = threadIdx.x >> 6;

    const float* p0 = which ? xs2 : x;
    const float* p1 = which ? xb1 : xs1;
    const float* p2 = which ? xb2 : xs2;

    const int n0 = chunk * 64;
    const size_t base = (size_t)b * NN;
    float acc = 0.0f;
    for (int j = w; j < 64; j += 4) {
        int n = n0 + j;
        size_t idx = (base + n) * NC + lane;
        float nf = (p0[idx] + p1[idx] + p2[idx]) * (1.0f / 3.0f);
        acc += nf * sc[((size_t)which * NB + b) * NN + n];
    }
    __shared__ float red[4][64];
    red[w][lane] = acc;
    __syncthreads();
    if (w == 0) {
        float s = red[0][lane] + red[1][lane] + red[2][lane] + red[3][lane];
        partial[(((size_t)which * NB + b) * 16 + chunk) * 64 + lane] = s;
    }
}

// ======= Stage D: reduce partials + multiply by weights1 =======
__global__ __launch_bounds__(256) void poolfin_kernel(
    const float* __restrict__ partial, const float* __restrict__ w1,
    float* __restrict__ gf_out)
{
    const int wb = blockIdx.x;
    const int t = threadIdx.x;
    const int lane = t & 63;
    const int w = t >> 6;

    __shared__ float red[4][64];
    __shared__ float gfin[64];
    float acc = 0.0f;
    #pragma unroll
    for (int r = w; r < 16; r += 4)
        acc += partial[((size_t)wb * 16 + r) * 64 + lane];
    red[w][lane] = acc;
    __syncthreads();
    if (w == 0) gfin[lane] = red[0][lane] + red[1][lane] + red[2][lane] + red[3][lane];
    __syncthreads();
    if (w == 0) {
        float s = 0.0f;
        #pragma unroll
        for (int c = 0; c < 64; ++c) s += gfin[c] * w1[c * 64 + lane];
        gf_out[(size_t)wb * 64 + lane] = s;
    }
}

// ------- wbuild_both_f16: one launch, writes SPLIT f16 W planes (halves W traffic) -------
__global__ __launch_bounds__(256) void wbuild_both_f16_kernel(
    const float* __restrict__ emb1, const float* __restrict__ wpf,
    const float* __restrict__ wpb,
    f16* __restrict__ Wfh, f16* __restrict__ Wfl,
    f16* __restrict__ Wbh, f16* __restrict__ Wbl)
{
    const int ki = blockIdx.x;            // 0..191
    const int chunk = blockIdx.y;         // 0..3
    const int which = blockIdx.z;         // 0: fwd, 1: bwd
    const float* pool = which ? wpb : wpf;
    f16* Wh = which ? Wbh : Wfh;
    f16* Wl = which ? Wbl : Wfl;
    const int t = threadIdx.x;
    const int o = t & 63;

    __shared__ float slab[16][64];
    __shared__ float eloc[256][16];

    for (int idx = t; idx < 1024; idx += 256)
        slab[idx >> 6][idx & 63] = pool[((size_t)(idx >> 6) * 192 + ki) * 64 + (idx & 63)];
    for (int idx = t; idx < 4096; idx += 256)
        eloc[idx >> 4][idx & 15] = emb1[((size_t)chunk * 256 + (idx >> 4)) * 16 + (idx & 15)];
    __syncthreads();
    for (int nl = t >> 6; nl < 256; nl += 4) {
        float s = 0.0f;
        #pragma unroll
        for (int e = 0; e < 16; ++e) s += eloc[nl][e] * slab[e][o];
        f16 h = (f16)s;
        f16 lo = (f16)(s - (float)h);
        size_t off = ((size_t)(chunk * 256 + nl) * 192 + ki) * 64 + o;
        Wh[off] = h;
        Wl[off] = lo;
    }
}

// ------- apply_mfma: per node, GEMM [32b x 192ki x 64o] x 2 dirs; W read as split f16 -------
__global__ __launch_bounds__(256) void apply_mfma_kernel(
    const f16* __restrict__ Wfh, const f16* __restrict__ Wfl,
    const f16* __restrict__ Wbh, const f16* __restrict__ Wbl,
    const float* __restrict__ emb1, const float* __restrict__ bias_pool,
    const float* __restrict__ x, const float* __restrict__ xs1, const float* __restrict__ xs2,
    const float* __restrict__ xb1, const float* __restrict__ xb2,
    const float* __restrict__ gf, const float* __restrict__ alpha, const float* __restrict__ beta,
    float* __restrict__ out)
{
    const int n = blockIdx.x;
    const int t = threadIdx.x;
    const int l = t & 63;
    const int g = l >> 5;
    const int l31 = l & 31;
    const int w = t >> 6;
    const int dir = w >> 1;   // 0: fwd (x,xs1,xs2), 1: bwd (xs2,xb1,xb2)
    const int ot  = w & 1;    // o-tile (32 cols)

    __shared__ __align__(16) f16 A5h[5][32 * A5STR], A5l[5][32 * A5STR];  // 45 KB
    __shared__ float e1s[16];

    if (t < 16) e1s[t] = emb1[n * 16 + t];

    const float* srcs[5] = {x, xs1, xs2, xb1, xb2};
    for (int idx = t; idx < 5 * 32 * 16; idx += 256) {
        int s = idx / (32 * 16);
        int rem = idx - s * (32 * 16);
        int b = rem >> 4, i4 = rem & 15;
        float4 v = *reinterpret_cast<const float4*>(srcs[s] + ((size_t)b * NN + n) * NC + i4 * 4);
        f16x4 ph, pl;
        ph[0] = (f16)v.x; pl[0] = (f16)(v.x - (float)ph[0]);
        ph[1] = (f16)v.y; pl[1] = (f16)(v.y - (float)ph[1]);
        ph[2] = (f16)v.z; pl[2] = (f16)(v.z - (float)ph[2]);
        ph[3] = (f16)v.w; pl[3] = (f16)(v.w - (float)ph[3]);
        *(f16x4*)&A5h[s][b * A5STR + i4 * 4] = ph;
        *(f16x4*)&A5l[s][b * A5STR + i4 * 4] = pl;
    }
    __syncthreads();

    const f16* whb = (dir ? Wbh : Wfh) + (size_t)n * 192 * 64 + ot * 32 + l31;
    const f16* wlb = (dir ? Wbl : Wfl) + (size_t)n * 192 * 64 + ot * 32 + l31;

    f32x16 acc;
    #pragma unroll
    for (int r = 0; r < 16; ++r) acc[r] = 0.0f;

    #pragma unroll 3
    for (int c = 0; c < 12; ++c) {        // 16-ki chunks
        const int ki0 = c * 16;
        const int s = dir * 2 + (ki0 >> 6);
        const int iloc = (ki0 & 63) + g * 8;
        f16x8 Ah = *(const f16x8*)&A5h[s][l31 * A5STR + iloc];
        f16x8 Al = *(const f16x8*)&A5l[s][l31 * A5STR + iloc];
        f16x8 Bh, Bl;
        #pragma unroll
        for (int j = 0; j < 8; ++j) {
            Bh[j] = whb[(size_t)(ki0 + g * 8 + j) * 64];
            Bl[j] = wlb[(size_t)(ki0 + g * 8 + j) * 64];
        }
        acc = __builtin_amdgcn_mfma_f32_32x32x16_f16(Al, Bh, acc, 0, 0, 0);
        acc = __builtin_amdgcn_mfma_f32_32x32x16_f16(Ah, Bl, acc, 0, 0, 0);
        acc = __builtin_amdgcn_mfma_f32_32x32x16_f16(Ah, Bh, acc, 0, 0, 0);
    }

    __syncthreads();
    float* red = reinterpret_cast<float*>(&A5h[0][0]);   // [2][32][33]
    if (dir == 1) {
        #pragma unroll
        for (int r = 0; r < 16; ++r) {
            int crow = (r & 3) + 8 * (r >> 2) + 4 * g;
            red[(ot * 32 + crow) * 33 + l31] = acc[r];
        }
    }
    __syncthreads();
    if (dir == 0) {
        const int o = ot * 32 + l31;
        float bias_o = 0.0f;
        #pragma unroll
        for (int e = 0; e < 16; ++e) bias_o += e1s[e] * bias_pool[e * 64 + o];
        const float al = alpha[0], be = beta[0];
        #pragma unroll
        for (int r = 0; r < 16; ++r) {
            int b = (r & 3) + 8 * (r >> 2) + 4 * g;
            float gv = gf[(size_t)b * 64 + o] + gf[((size_t)NB + b) * 64 + o];
            out[((size_t)b * NN + n) * NC + o] =
                al * acc[r] + be * red[(ot * 32 + b) * 33 + l31] + bias_o + gv;
        }
    }
}

// ------- Fallback old wbuild/apply (ws-tier) -------
__global__ __launch_bounds__(256) void wbuild_kernel(
    const float* __restrict__ emb1, const float* __restrict__ pool,
    float* __restrict__ W)
{
    const int ki = blockIdx.x;
    const int chunk = blockIdx.y;
    const int t = threadIdx.x;
    const int o = t & 63;

    __shared__ float slab[16][64];
    __shared__ float eloc[256][16];

    for (int idx = t; idx < 1024; idx += 256)
        slab[idx >> 6][idx & 63] = pool[((size_t)(idx >> 6) * 192 + ki) * 64 + (idx & 63)];
    for (int idx = t; idx < 4096; idx += 256)
        eloc[idx >> 4][idx & 15] = emb1[((size_t)chunk * 256 + (idx >> 4)) * 16 + (idx & 15)];
    __syncthreads();
    for (int nl = t >> 6; nl < 256; nl += 4) {
        float s = 0.0f;
        #pragma unroll
        for (int e = 0; e < 16; ++e) s += eloc[nl][e] * slab[e][o];
        W[((size_t)(chunk * 256 + nl) * 192 + ki) * 64 + o] = s;
    }
}

__global__ __launch_bounds__(256) void apply_kernel(
    const float* __restrict__ W, const float* __restrict__ emb1,
    const float* __restrict__ bias_pool,
    const float* __restrict__ s0, const float* __restrict__ s1, const float* __restrict__ s2,
    const float* __restrict__ gf, const float* __restrict__ scale,
    float* __restrict__ out, int pass)
{
    const int n = blockIdx.x;
    const int t = threadIdx.x;
    const int o = t & 63;
    const int bg = t >> 6;

    __shared__ float Wn[192][64];
    __shared__ float Xs[3][32][64];
    __shared__ float e1s[16];

    if (t < 16) e1s[t] = emb1[n * 16 + t];
    {
        const float4* src = reinterpret_cast<const float4*>(W + (size_t)n * 192 * 64);
        float4* dst = reinterpret_cast<float4*>(&Wn[0][0]);
        #pragma unroll
        for (int r = 0; r < 12; ++r) dst[t + 256 * r] = src[t + 256 * r];
    }
    const float* srcs[3] = {s0, s1, s2};
    #pragma unroll
    for (int k = 0; k < 3; ++k) {
        const float* sp = srcs[k];
        #pragma unroll
        for (int r = 0; r < 2; ++r) {
            int idx = t + 256 * r;
            int b = idx >> 4, i4 = idx & 15;
            reinterpret_cast<float4*>(&Xs[k][b][0])[i4] =
                reinterpret_cast<const float4*>(sp + ((size_t)b * NN + n) * NC)[i4];
        }
    }
    __syncthreads();

    float acc[8] = {};
    #pragma unroll 4
    for (int ki = 0; ki < 192; ++ki) {
        float wv = Wn[ki][o];
        int k = ki >> 6, i = ki & 63;
        #pragma unroll
        for (int j = 0; j < 8; ++j) acc[j] += Xs[k][bg * 8 + j][i] * wv;
    }

    const float sc = scale[0];
    if (pass == 0) {
        float bias_o = 0.0f;
        #pragma unroll
        for (int e = 0; e < 16; ++e) bias_o += e1s[e] * bias_pool[e * 64 + o];
        #pragma unroll
        for (int j = 0; j < 8; ++j) {
            int b = bg * 8 + j;
            float g = gf[(size_t)b * 64 + o] + gf[((size_t)NB + b) * 64 + o];
            out[((size_t)b * NN + n) * NC + o] = sc * acc[j] + bias_o + g;
        }
    } else {
        #pragma unroll
        for (int j = 0; j < 8; ++j) {
            int b = bg * 8 + j;
            out[((size_t)b * NN + n) * NC + o] += sc * acc[j];
        }
    }
}

// ------- Fallback final kernel (ws too small) -------
__global__ __launch_bounds__(256) void final_kernel(
    const float* __restrict__ emb1,
    const float* __restrict__ wpf, const float* __restrict__ wpb,
    const float* __restrict__ bias_pool,
    const float* __restrict__ x, const float* __restrict__ xs1, const float* __restrict__ xs2,
    const float* __restrict__ xb1, const float* __restrict__ xb2,
    const float* __restrict__ gf, const float* __restrict__ alpha, const float* __restrict__ beta,
    float* __restrict__ out)
{
    const int n = blockIdx.x;
    const int t = threadIdx.x;
    const int o = t & 63;
    const int bg = t >> 6;

    __shared__ float Wk[64][64];
    __shared__ float xk[32][64];
    __shared__ float e1[16];
    if (t < 16) e1[t] = emb1[n * 16 + t];

    float acc[2][8];
    #pragma unroll
    for (int d = 0; d < 2; ++d)
        #pragma unroll
        for (int j = 0; j < 8; ++j) acc[d][j] = 0.0f;

    const float* srcs[2][3] = {{x, xs1, xs2}, {xs2, xb1, xb2}};

    #pragma unroll
    for (int dir = 0; dir < 2; ++dir) {
        const float* wp = dir ? wpb : wpf;
        #pragma unroll
        for (int k = 0; k < 3; ++k) {
            __syncthreads();
            for (int idx = t; idx < 4096; idx += 256) {
                int i = idx >> 6, oo = idx & 63;
                float s = 0.0f;
                #pragma unroll
                for (int e = 0; e < 16; ++e) s += e1[e] * wp[(((size_t)e * 3 + k) * 64 + i) * 64 + oo];
                Wk[i][oo] = s;
            }
            const float* src = srcs[dir][k];
            for (int idx = t; idx < 2048; idx += 256) {
                int bb = idx >> 6, ii = idx & 63;
                xk[bb][ii] = src[((size_t)bb * NN + n) * NC + ii];
            }
            __syncthreads();
            #pragma unroll
            for (int j = 0; j < 8; ++j) {
                int bb = bg * 8 + j;
                float s = 0.0f;
                #pragma unroll
                for (int i = 0; i < 64; i += 4) {
                    float4 xv = *reinterpret_cast<const float4*>(&xk[bb][i]);
                    s += xv.x * Wk[i][o] + xv.y * Wk[i + 1][o] + xv.z * Wk[i + 2][o] + xv.w * Wk[i + 3][o];
                }
                acc[dir][j] += s;
            }
        }
    }

    float bias_o = 0.0f;
    #pragma unroll
    for (int e = 0; e < 16; ++e) bias_o += e1[e] * bias_pool[e * 64 + o];
    const float al = alpha[0], be = beta[0];
    #pragma unroll
    for (int j = 0; j < 8; ++j) {
        int bb = bg * 8 + j;
        float g = gf[(size_t)bb * 64 + o] + gf[((size_t)NB + bb) * 64 + o];
        out[((size_t)bb * NN + n) * NC + o] = al * acc[0][j] + be * acc[1][j] + bias_o + g;
    }
}

// ------- Fallback attnpool (ws too small) -------
__global__ __launch_bounds__(256) void attnpool_kernel(
    const float* __restrict__ a0, const float* __restrict__ a1, const float* __restrict__ a2,
    const float* __restrict__ c0, const float* __restrict__ c1, const float* __restrict__ c2,
    const float* __restrict__ att_w, const float* __restrict__ att_b,
    const float* __restrict__ w1, float* __restrict__ gf_out)
{
    const int b = blockIdx.x;
    const int which = blockIdx.y;
    const float* p0 = which ? c0 : a0;
    const float* p1 = which ? c1 : a1;
    const float* p2 = which ? c2 : a2;
    const int t = threadIdx.x;
    const int lane = t & 63;
    const int w = t >> 6;

    __shared__ float sc[NN];
    __shared__ float red[4];
    __shared__ float gfp[4][64];
    __shared__ float gfin[64];

    const float aw = att_w[lane];
    const size_t base = (size_t)b * NN * NC;

    for (int n = w; n < NN; n += 4) {
        size_t idx = base + (size_t)n * NC + lane;
        float nf = (p0[idx] + p1[idx] + p2[idx]) * (1.0f / 3.0f);
        float v = nf * aw;
        #pragma unroll
        for (int off = 32; off > 0; off >>= 1) v += __shfl_xor(v, off);
        if (lane == 0) sc[n] = v + att_b[0];
    }
    __syncthreads();
    float m = -INFINITY;
    for (int i = t; i < NN; i += 256) m = fmaxf(m, sc[i]);
    #pragma unroll
    for (int off = 32; off > 0; off >>= 1) m = fmaxf(m, __shfl_xor(m, off));
    if (lane == 0) red[w] = m;
    __syncthreads();
    m = fmaxf(fmaxf(red[0], red[1]), fmaxf(red[2], red[3]));
    __syncthreads();
    float s = 0.0f;
    for (int i = t; i < NN; i += 256) { float e = expf(sc[i] - m); sc[i] = e; s += e; }
    #pragma unroll
    for (int off = 32; off > 0; off >>= 1) s += __shfl_xor(s, off);
    if (lane == 0) red[w] = s;
    __syncthreads();
    const float inv_denom = 1.0f / (red[0] + red[1] + red[2] + red[3]);

    float acc = 0.0f;
    for (int n = w; n < NN; n += 4) {
        size_t idx = base + (size_t)n * NC + lane;
        float nf = (p0[idx] + p1[idx] + p2[idx]) * (1.0f / 3.0f);
        acc += nf * sc[n];
    }
    gfp[w][lane] = acc;
    __syncthreads();
    if (w == 0) gfin[lane] = (gfp[0][lane] + gfp[1][lane] + gfp[2][lane] + gfp[3][lane]) * inv_denom;
    __syncthreads();
    if (w == 0) {
        float s2 = 0.0f;
        #pragma unroll
        for (int c = 0; c < 64; ++c) s2 += gfin[c] * w1[c * 64 + lane];
        gf_out[((size_t)which * NB + b) * 64 + lane] = s2;
    }
}

extern "C" void kernel_launch(void* const* d_in, const int* in_sizes, int n_in,
                              void* d_out, int out_size, void* d_ws, size_t ws_size,
                              hipStream_t stream)
{
    const float* x      = (const float*)d_in[0];
    const float* emb0   = (const float*)d_in[1];
    const float* emb1   = (const float*)d_in[2];
    const float* speed  = (const float*)d_in[5];
    const float* occupy = (const float*)d_in[6];
    const float* fw1 = (const float*)d_in[7];
    const float* fb1 = (const float*)d_in[8];
    const float* fw2 = (const float*)d_in[9];
    const float* fb2 = (const float*)d_in[10];
    const float* fw3 = (const float*)d_in[11];
    const float* fb3 = (const float*)d_in[12];
    const float* gw1 = (const float*)d_in[13];
    const float* gb1 = (const float*)d_in[14];
    const float* gw2 = (const float*)d_in[15];
    const float* gb2 = (const float*)d_in[16];
    const float* gw3 = (const float*)d_in[17];
    const float* gb3 = (const float*)d_in[18];
    const float* alpha = (const float*)d_in[19];
    const float* beta  = (const float*)d_in[20];
    const float* wpf = (const float*)d_in[21];
    const float* wpb = (const float*)d_in[22];
    const float* bias_pool = (const float*)d_in[23];
    const float* w1 = (const float*)d_in[24];
    const float* att_w = (const float*)d_in[25];
    const float* att_b = (const float*)d_in[26];
    float* out = (float*)d_out;

    float* ws = (float*)d_ws;
    float* nv  = ws;                                   // B*N*E
    float* xs1 = nv + (size_t)NB * NN * NE;            // B*N*C each
    float* xs2 = xs1 + (size_t)NB * NN * NC;
    float* xb1 = xs2 + (size_t)NB * NN * NC;
    float* xb2 = xb1 + (size_t)NB * NN * NC;
    float* gfb = xb2 + (size_t)NB * NN * NC;           // [2][B][64]
    float* scb = gfb + 4096;                           // [2][B][N]
    float* ppb = scb + (size_t)2 * NB * NN;            // [2][B][16][64]
    float* Wbuf = ppb + (size_t)2 * NB * 16 * 64;      // N*192*64 f32 region
    f16* Sh = (f16*)(Wbuf + (size_t)NN * 192 * 64);    // B*N*N f16 planes
    f16* Sl = Sh + (size_t)NB * NN * NN;
    f16* T0h = Sl + (size_t)NB * NN * NN;              // B*C*N transposed split planes
    f16* T0l = T0h + (size_t)NB * NC * NN;
    f16* T1h = T0l + (size_t)NB * NC * NN;
    f16* T1l = T1h + (size_t)NB * NC * NN;
    // split-f16 W planes: fwd in the Wbuf region (same byte footprint), bwd aliased on dead S
    f16* Wfh = (f16*)Wbuf;
    f16* Wfl = Wfh + (size_t)NN * 192 * 64;
    f16* Wbh = (f16*)Sh;
    f16* Wbl = Wbh + (size_t)NN * 192 * 64;

    const size_t base_elems = (size_t)NB * NN * NE + 4 * (size_t)NB * NN * NC + 4096;
    const size_t attn_elems = (size_t)2 * NB * NN + (size_t)2 * NB * 16 * 64;
    const size_t w_elems = (size_t)NN * 192 * 64;
    const size_t need_mid = (base_elems + attn_elems + w_elems) * sizeof(float);
    const size_t need_full = need_mid +
        ((size_t)2 * NB * NN * NN + (size_t)4 * NB * NC * NN) * sizeof(f16);

    if (ws_size >= need_full) {
        hipLaunchKernelGGL(nvxsplit_kernel, dim3(NB * 16 + NB * NN / 256), dim3(256), 0, stream,
                           x, emb0, speed, occupy, fw1, fb1, fw2, fb2, fw3, fb3,
                           gw1, gb1, gw2, gb2, gw3, gb3, nv, T0h, T0l);
        hipLaunchKernelGGL(sgen_fused_kernel, dim3(NB, NN / 128), dim3(512), 0, stream,
                           nv, T0h, T0l, Sh, Sl, xs1, T1h, T1l);
        dim3 gd5(NB, NN / 64);
        hipLaunchKernelGGL(diffuse5_kernel, gd5, dim3(256), 0, stream,
                           Sh, Sl, T1h, T1l, xs2, T0h, T0l, 1);
        hipLaunchKernelGGL(diffuse5_kernel, gd5, dim3(256), 0, stream,
                           Sh, Sl, T0h, T0l, xb1, T1h, T1l, 1);
        hipLaunchKernelGGL(diffuse5_kernel, gd5, dim3(256), 0, stream,
                           Sh, Sl, T1h, T1l, xb2, T0h, T0l, 0);
        // attention pool
        hipLaunchKernelGGL(scores_kernel, dim3(2 * NB * NN / 4), dim3(256), 0, stream,
                           x, xs1, xs2, xb1, xb2, att_w, att_b, scb);
        hipLaunchKernelGGL(poolpart2_kernel, dim3(16, NB, 2), dim3(256), 0, stream,
                           x, xs1, xs2, xb1, xb2, scb, ppb);
        hipLaunchKernelGGL(poolfin_kernel, dim3(2 * NB), dim3(256), 0, stream, ppb, w1, gfb);
        // final stage: split-f16 W build + MFMA apply
        hipLaunchKernelGGL(wbuild_both_f16_kernel, dim3(192, 4, 2), dim3(256), 0, stream,
                           emb1, wpf, wpb, Wfh, Wfl, Wbh, Wbl);
        hipLaunchKernelGGL(apply_mfma_kernel, dim3(NN), dim3(256), 0, stream,
                           Wfh, Wfl, Wbh, Wbl, emb1, bias_pool, x, xs1, xs2, xb1, xb2,
                           gfb, alpha, beta, out);
    } else if (ws_size >= need_mid) {
        hipLaunchKernelGGL(nv_kernel, dim3(NB * NN / 64), dim3(64), 0, stream,
                           x, emb0, speed, occupy, fw1, fb1, fw2, fb2, fw3, fb3,
                           gw1, gb1, gw2, gb2, gw3, gb3, nv);
        dim3 gd(NB, NN / 128);
        hipLaunchKernelGGL(diffuse_mfma_kernel, gd, dim3(256), 0, stream, nv, x, xs1);
        hipLaunchKernelGGL(diffuse_mfma_kernel, gd, dim3(256), 0, stream, nv, xs1, xs2);
        hipLaunchKernelGGL(diffuse_mfma_kernel, gd, dim3(256), 0, stream, nv, xs2, xb1);
        hipLaunchKernelGGL(diffuse_mfma_kernel, gd, dim3(256), 0, stream, nv, xb1, xb2);
        hipLaunchKernelGGL(scores_kernel, dim3(2 * NB * NN / 4), dim3(256), 0, stream,
                           x, xs1, xs2, xb1, xb2, att_w, att_b, scb);
        hipLaunchKernelGGL(softmax_kernel, dim3(2 * NB), dim3(256), 0, stream, scb);
        hipLaunchKernelGGL(poolpart_kernel, dim3(16, NB, 2), dim3(256), 0, stream,
                           x, xs1, xs2, xb1, xb2, scb, ppb);
        hipLaunchKernelGGL(poolfin_kernel, dim3(2 * NB), dim3(256), 0, stream, ppb, w1, gfb);
        hipLaunchKernelGGL(wbuild_kernel, dim3(192, 4), dim3(256), 0, stream, emb1, wpf, Wbuf);
        hipLaunchKernelGGL(apply_kernel, dim3(NN), dim3(256), 0, stream,
                           Wbuf, emb1, bias_pool, x, xs1, xs2, gfb, alpha, out, 0);
        hipLaunchKernelGGL(wbuild_kernel, dim3(192, 4), dim3(256), 0, stream, emb1, wpb, Wbuf);
        hipLaunchKernelGGL(apply_kernel, dim3(NN), dim3(256), 0, stream,
                           Wbuf, emb1, bias_pool, xs2, xb1, xb2, gfb, beta, out, 1);
    } else {
        hipLaunchKernelGGL(nv_kernel, dim3(NB * NN / 64), dim3(64), 0, stream,
                           x, emb0, speed, occupy, fw1, fb1, fw2, fb2, fw3, fb3,
                           gw1, gb1, gw2, gb2, gw3, gb3, nv);
        dim3 gd(NB, NN / 128);
        hipLaunchKernelGGL(diffuse_mfma_kernel, gd, dim3(256), 0, stream, nv, x, xs1);
        hipLaunchKernelGGL(diffuse_mfma_kernel, gd, dim3(256), 0, stream, nv, xs1, xs2);
        hipLaunchKernelGGL(diffuse_mfma_kernel, gd, dim3(256), 0, stream, nv, xs2, xb1);
        hipLaunchKernelGGL(diffuse_mfma_kernel, gd, dim3(256), 0, stream, nv, xb1, xb2);
        hipLaunchKernelGGL(attnpool_kernel, dim3(NB, 2), dim3(256), 0, stream,
                           x, xs1, xs2, xs2, xb1, xb2, att_w, att_b, w1, gfb);
        hipLaunchKernelGGL(final_kernel, dim3(NN), dim3(256), 0, stream,
                           emb1, wpf, wpb, bias_pool, x, xs1, xs2, xb1, xb2, gfb, alpha, beta, out);
    }
}

// Round 17
// 240.122 us; speedup vs baseline: 1.0172x; 1.0172x over previous
//
#include <hip/hip_runtime.h>
#include <cmath>

#define NB 32
#define NN 1024
#define NC 64
#define NE 16

typedef _Float16 f16;
typedef __attribute__((ext_vector_type(2))) _Float16 f16x2;
typedef __attribute__((ext_vector_type(4))) _Float16 f16x4;
typedef __attribute__((ext_vector_type(8))) _Float16 f16x8;
typedef __attribute__((ext_vector_type(16))) float f32x16;

#define NVSTR 24
#define SSTR  40
#define XSTR  40
#define ASTR  40
#define A5STR 72

__device__ __forceinline__ float sigm(float v) { return 1.0f / (1.0f + expf(-v)); }
__device__ __forceinline__ float lrelu(float v) { return v > 0.0f ? v : 0.01f * v; }

// ---------------- nv body (one thread per row) as device function ----------------
__device__ __forceinline__ void nv_row(
    int row,
    const float* __restrict__ x, const float* __restrict__ emb0,
    const float* __restrict__ speed, const float* __restrict__ occupy,
    const float* __restrict__ fw1, const float* __restrict__ fb1,
    const float* __restrict__ fw2, const float* __restrict__ fb2,
    const float* __restrict__ fw3, const float* __restrict__ fb3,
    const float* __restrict__ gw1, const float* __restrict__ gb1,
    const float* __restrict__ gw2, const float* __restrict__ gb2,
    const float* __restrict__ gw3, const float* __restrict__ gb3,
    float* __restrict__ nv_out)
{
    float h1[16];
    #pragma unroll
    for (int j = 0; j < 16; ++j) h1[j] = fb1[j];
    {
        const float4* xr = reinterpret_cast<const float4*>(x + (size_t)row * 64);
        #pragma unroll
        for (int i4 = 0; i4 < 16; ++i4) {
            float4 xv = xr[i4];
            #pragma unroll
            for (int j = 0; j < 16; ++j) {
                const float* wr = fw1 + j * 64 + i4 * 4;
                h1[j] += xv.x * wr[0] + xv.y * wr[1] + xv.z * wr[2] + xv.w * wr[3];
            }
        }
    }
    #pragma unroll
    for (int j = 0; j < 16; ++j) h1[j] = sigm(h1[j]);

    float h2a = fb2[0], h2b = fb2[1];
    #pragma unroll
    for (int j = 0; j < 16; ++j) { h2a += h1[j] * fw2[j]; h2b += h1[j] * fw2[16 + j]; }
    h2a = sigm(h2a); h2b = sigm(h2b);

    const float sp = speed[row], oc = occupy[row];
    float ga = gb2[0], gb_ = gb2[1];
    float oa = gb2[0], ob_ = gb2[1];
    #pragma unroll
    for (int j = 0; j < 16; ++j) {
        float g1 = sigm(sp * gw1[j] + gb1[j]);
        float o1 = sigm(oc * gw1[j] + gb1[j]);
        ga += g1 * gw2[j];  gb_ += g1 * gw2[16 + j];
        oa += o1 * gw2[j];  ob_ += o1 * gw2[16 + j];
    }
    ga = sigm(ga); gb_ = sigm(gb_); oa = sigm(oa); ob_ = sigm(ob_);

    const float* e0 = emb0 + (size_t)row * 16;
    float vout[16];
    #pragma unroll
    for (int j = 0; j < 16; ++j) {
        float filt = h2a * fw3[j * 2] + h2b * fw3[j * 2 + 1] + fb3[j];
        float f1v  = ga  * gw3[j * 2] + gb_ * gw3[j * 2 + 1] + gb3[j];
        float f2v  = oa  * gw3[j * 2] + ob_ * gw3[j * 2 + 1] + gb3[j];
        float v = tanhf(e0[j] * filt);
        v = tanhf(v * f1v);
        v = tanhf(v * f2v);
        vout[j] = v;
    }
    float4* dst = reinterpret_cast<float4*>(nv_out + (size_t)row * 16);
    #pragma unroll
    for (int q = 0; q < 4; ++q) {
        float4 o; o.x = vout[4 * q]; o.y = vout[4 * q + 1]; o.z = vout[4 * q + 2]; o.w = vout[4 * q + 3];
        dst[q] = o;
    }
}

// ---------------- Fallback nv kernel (mid/low tiers) ----------------
__global__ __launch_bounds__(64) void nv_kernel(
    const float* __restrict__ x, const float* __restrict__ emb0,
    const float* __restrict__ speed, const float* __restrict__ occupy,
    const float* __restrict__ fw1, const float* __restrict__ fb1,
    const float* __restrict__ fw2, const float* __restrict__ fb2,
    const float* __restrict__ fw3, const float* __restrict__ fb3,
    const float* __restrict__ gw1, const float* __restrict__ gb1,
    const float* __restrict__ gw2, const float* __restrict__ gb2,
    const float* __restrict__ gw3, const float* __restrict__ gb3,
    float* __restrict__ nv_out)
{
    nv_row(blockIdx.x * 64 + threadIdx.x, x, emb0, speed, occupy,
           fw1, fb1, fw2, fb2, fw3, fb3, gw1, gb1, gw2, gb2, gw3, gb3, nv_out);
}

// ---------------- nvxsplit: fused nv + x transpose/split (one launch) ----------------
__global__ __launch_bounds__(256) void nvxsplit_kernel(
    const float* __restrict__ x, const float* __restrict__ emb0,
    const float* __restrict__ speed, const float* __restrict__ occupy,
    const float* __restrict__ fw1, const float* __restrict__ fb1,
    const float* __restrict__ fw2, const float* __restrict__ fb2,
    const float* __restrict__ fw3, const float* __restrict__ fb3,
    const float* __restrict__ gw1, const float* __restrict__ gb1,
    const float* __restrict__ gw2, const float* __restrict__ gb2,
    const float* __restrict__ gw3, const float* __restrict__ gb3,
    float* __restrict__ nv_out, f16* __restrict__ Th, f16* __restrict__ Tl)
{
    __shared__ float tile[64][65];
    const int t = threadIdx.x;

    if ((int)blockIdx.x < NB * 16) {
        const int b = blockIdx.x >> 4;
        const int n0 = (blockIdx.x & 15) * 64;
        {
            int r = t >> 2;
            const float4* src = reinterpret_cast<const float4*>(x + ((size_t)b * NN + n0 + r) * NC);
            #pragma unroll
            for (int i = 0; i < 4; ++i) {
                int fi = (t & 3) + 4 * i;
                float4 vv = src[fi];
                tile[r][fi * 4 + 0] = vv.x; tile[r][fi * 4 + 1] = vv.y;
                tile[r][fi * 4 + 2] = vv.z; tile[r][fi * 4 + 3] = vv.w;
            }
        }
        __syncthreads();
        const int c = t & 63, ng = (t >> 6) * 16;
        f16x8 ph0, ph1, pl0, pl1;
        #pragma unroll
        for (int j = 0; j < 8; ++j) {
            float v = tile[ng + j][c];
            f16 h = (f16)v; ph0[j] = h; pl0[j] = (f16)(v - (float)h);
        }
        #pragma unroll
        for (int j = 0; j < 8; ++j) {
            float v = tile[ng + 8 + j][c];
            f16 h = (f16)v; ph1[j] = h; pl1[j] = (f16)(v - (float)h);
        }
        f16* dh = Th + ((size_t)b * NC + c) * NN + n0 + ng;
        f16* dl = Tl + ((size_t)b * NC + c) * NN + n0 + ng;
        *(f16x8*)dh = ph0; *(f16x8*)(dh + 8) = ph1;
        *(f16x8*)dl = pl0; *(f16x8*)(dl + 8) = pl1;
    } else {
        const int row = ((int)blockIdx.x - NB * 16) * 256 + t;
        nv_row(row, x, emb0, speed, occupy,
               fw1, fb1, fw2, fb2, fw3, fb3, gw1, gb1, gw2, gb2, gw3, gb3, nv_out);
    }
}

// ------- sgen_fused: S = relu(nv nv^T) materialized AND step-1 y = lrelu(S x) in one pass -------
__global__ __launch_bounds__(512, 2) void sgen_fused_kernel(
    const float* __restrict__ nv,
    const f16* __restrict__ xTh, const f16* __restrict__ xTl,
    f16* __restrict__ Sh, f16* __restrict__ Sl,
    float* __restrict__ yout, f16* __restrict__ yTh, f16* __restrict__ yTl)
{
    const int b = blockIdx.x;
    const int m0 = blockIdx.y * 128;
    const int t = threadIdx.x;
    const int l = t & 63;
    const int g = l >> 5;
    const int l31 = l & 31;
    const int w = t >> 6;
    const int mq = w >> 1;
    const int nh = w & 1;

    __shared__ __align__(16) f16 nvBh[128 * NVSTR], nvBl[128 * NVSTR];
    __shared__ __align__(16) f16 Xsh[4][64 * XSTR], Xsl[4][64 * XSTR];
    __shared__ __align__(16) f16 Sth[4][128 * SSTR], Stl[4][128 * SSTR];

    const size_t sbase = (size_t)b * NN * NN;

    {
        int row = t >> 2, e0 = (t & 3) * 4;
        const float* src = nv + ((size_t)b * NN + m0 + row) * NE + e0;
        float v0 = src[0], v1 = src[1], v2 = src[2], v3 = src[3];
        f16x4 ph, pl;
        ph[0] = (f16)v0; pl[0] = (f16)(v0 - (float)ph[0]);
        ph[1] = (f16)v1; pl[1] = (f16)(v1 - (float)ph[1]);
        ph[2] = (f16)v2; pl[2] = (f16)(v2 - (float)ph[2]);
        ph[3] = (f16)v3; pl[3] = (f16)(v3 - (float)ph[3]);
        *(f16x4*)&Sth[0][row * NVSTR + e0] = ph;
        *(f16x4*)&Stl[0][row * NVSTR + e0] = pl;
    }
    __syncthreads();
    f16x8 Ah = *(const f16x8*)&Sth[0][(mq * 32 + l31) * NVSTR + g * 8];
    f16x8 Al = *(const f16x8*)&Stl[0][(mq * 32 + l31) * NVSTR + g * 8];

    f32x16 acc0, acc1;
    #pragma unroll
    for (int r = 0; r < 16; ++r) { acc0[r] = 0.0f; acc1[r] = 0.0f; }

    const int brow = t >> 2, be0 = (t & 3) * 4;
    const int xc = t >> 3, xpart = t & 7;
    const int xsub = xpart >> 1, xhalf = xpart & 1;

    for (int it = 0; it < 8; ++it) {
        {
            const float* src = nv + ((size_t)b * NN + it * 128 + brow) * NE + be0;
            float v0 = src[0], v1 = src[1], v2 = src[2], v3 = src[3];
            f16x4 ph, pl;
            ph[0] = (f16)v0; pl[0] = (f16)(v0 - (float)ph[0]);
            ph[1] = (f16)v1; pl[1] = (f16)(v1 - (float)ph[1]);
            ph[2] = (f16)v2; pl[2] = (f16)(v2 - (float)ph[2]);
            ph[3] = (f16)v3; pl[3] = (f16)(v3 - (float)ph[3]);
            *(f16x4*)&nvBh[brow * NVSTR + be0] = ph;
            *(f16x4*)&nvBl[brow * NVSTR + be0] = pl;
        }
        {
            const f16* sH = xTh + ((size_t)b * NC + xc) * NN + it * 128 + xsub * 32 + xhalf * 16;
            const f16* sL = xTl + ((size_t)b * NC + xc) * NN + it * 128 + xsub * 32 + xhalf * 16;
            *(f16x8*)&Xsh[xsub][xc * XSTR + xhalf * 16] = *(const f16x8*)sH;
            *(f16x8*)&Xsh[xsub][xc * XSTR + xhalf * 16 + 8] = *(const f16x8*)(sH + 8);
            *(f16x8*)&Xsl[xsub][xc * XSTR + xhalf * 16] = *(const f16x8*)sL;
            *(f16x8*)&Xsl[xsub][xc * XSTR + xhalf * 16 + 8] = *(const f16x8*)(sL + 8);
        }
        __syncthreads();

        #pragma unroll
        for (int tl = 0; tl < 2; ++tl) {
            const int tile = nh * 2 + tl;
            f16x8 Bh = *(const f16x8*)&nvBh[(tile * 32 + l31) * NVSTR + g * 8];
            f16x8 Bl = *(const f16x8*)&nvBl[(tile * 32 + l31) * NVSTR + g * 8];
            f32x16 sa;
            #pragma unroll
            for (int r = 0; r < 16; ++r) sa[r] = 0.0f;
            sa = __builtin_amdgcn_mfma_f32_32x32x16_f16(Al, Bh, sa, 0, 0, 0);
            sa = __builtin_amdgcn_mfma_f32_32x32x16_f16(Ah, Bl, sa, 0, 0, 0);
            sa = __builtin_amdgcn_mfma_f32_32x32x16_f16(Ah, Bh, sa, 0, 0, 0);
            const int n = it * 128 + tile * 32 + l31;
            #pragma unroll
            for (int r = 0; r < 16; ++r) {
                float vv = fmaxf(sa[r], 0.0f);
                f16 h = (f16)vv; f16 lo = (f16)(vv - (float)h);
                int mloc = mq * 32 + (r & 3) + 8 * (r >> 2) + 4 * g;
                Sh[sbase + (size_t)(m0 + mloc) * NN + n] = h;
                Sl[sbase + (size_t)(m0 + mloc) * NN + n] = lo;
                Sth[tile][mloc * SSTR + l31] = h;
                Stl[tile][mloc * SSTR + l31] = lo;
            }
        }
        __syncthreads();

        #pragma unroll
        for (int tl = 0; tl < 2; ++tl) {
            const int tile = nh * 2 + tl;
            #pragma unroll
            for (int ku = 0; ku < 2; ++ku) {
                f16x8 Ah2 = *(const f16x8*)&Sth[tile][(mq * 32 + l31) * SSTR + ku * 16 + g * 8];
                f16x8 Al2 = *(const f16x8*)&Stl[tile][(mq * 32 + l31) * SSTR + ku * 16 + g * 8];
                {
                    f16x8 Bh = *(const f16x8*)&Xsh[tile][l31 * XSTR + ku * 16 + g * 8];
                    f16x8 Bl = *(const f16x8*)&Xsl[tile][l31 * XSTR + ku * 16 + g * 8];
                    acc0 = __builtin_amdgcn_mfma_f32_32x32x16_f16(Al2, Bh, acc0, 0, 0, 0);
                    acc0 = __builtin_amdgcn_mfma_f32_32x32x16_f16(Ah2, Bl, acc0, 0, 0, 0);
                    acc0 = __builtin_amdgcn_mfma_f32_32x32x16_f16(Ah2, Bh, acc0, 0, 0, 0);
                }
                {
                    f16x8 Bh = *(const f16x8*)&Xsh[tile][(32 + l31) * XSTR + ku * 16 + g * 8];
                    f16x8 Bl = *(const f16x8*)&Xsl[tile][(32 + l31) * XSTR + ku * 16 + g * 8];
                    acc1 = __builtin_amdgcn_mfma_f32_32x32x16_f16(Al2, Bh, acc1, 0, 0, 0);
                    acc1 = __builtin_amdgcn_mfma_f32_32x32x16_f16(Ah2, Bl, acc1, 0, 0, 0);
                    acc1 = __builtin_amdgcn_mfma_f32_32x32x16_f16(Ah2, Bh, acc1, 0, 0, 0);
                }
            }
        }
        __syncthreads();
    }

    float* red = reinterpret_cast<float*>(&Sth[0][0]);
    if (nh == 1) {
        #pragma unroll
        for (int r = 0; r < 16; ++r) {
            int crow = (r & 3) + 8 * (r >> 2) + 4 * g;
            red[((mq * 2 + 0) * 32 + crow) * 33 + l31] = acc0[r];
            red[((mq * 2 + 1) * 32 + crow) * 33 + l31] = acc1[r];
        }
    }
    __syncthreads();
    if (nh == 0) {
        #pragma unroll
        for (int ch = 0; ch < 2; ++ch) {
            const int colg = ch * 32 + l31;
            #pragma unroll
            for (int q = 0; q < 4; ++q) {
                float v[4];
                #pragma unroll
                for (int j = 0; j < 4; ++j) {
                    int r = q * 4 + j;
                    int crow = j + 8 * q + 4 * g;
                    float part = (ch == 0) ? acc0[r] : acc1[r];
                    v[j] = lrelu(part + red[((mq * 2 + ch) * 32 + crow) * 33 + l31]);
                }
                const int mrow = m0 + mq * 32 + 8 * q + 4 * g;
                #pragma unroll
                for (int j = 0; j < 4; ++j)
                    yout[((size_t)b * NN + mrow + j) * NC + colg] = v[j];
                f16x4 ph, pl;
                #pragma unroll
                for (int j = 0; j < 4; ++j) {
                    f16 h = (f16)v[j];
                    ph[j] = h; pl[j] = (f16)(v[j] - (float)h);
                }
                *(f16x4*)&yTh[((size_t)b * NC + colg) * NN + mrow] = ph;
                *(f16x4*)&yTl[((size_t)b * NC + colg) * NN + mrow] = pl;
            }
        }
    }
}

// ------- diffuse5: y = lrelu(S x); M=64, 4 waves (mh,ch), pure-b128 staging from planes -------
__global__ __launch_bounds__(256) void diffuse5_kernel(
    const f16* __restrict__ Sh, const f16* __restrict__ Sl,
    const f16* __restrict__ xTh, const f16* __restrict__ xTl,
    float* __restrict__ yout, f16* __restrict__ yTh, f16* __restrict__ yTl,
    int writeT)
{
    const int b = blockIdx.x;
    const int m0 = blockIdx.y * 64;
    const int t = threadIdx.x;
    const int l = t & 63;
    const int g = l >> 5;
    const int l31 = l & 31;
    const int w = t >> 6;
    const int mh = w & 1;
    const int ch = w >> 1;

    __shared__ __align__(16) f16 As_h[2][64 * ASTR], As_l[2][64 * ASTR];
    __shared__ __align__(16) f16 Xs_h[2][64 * XSTR], Xs_l[2][64 * XSTR];

    const int arow = t >> 2, akc = t & 3;
    const f16* Ah_src = Sh + (size_t)b * NN * NN + (size_t)(m0 + arow) * NN + akc * 8;
    const f16* Al_src = Sl + (size_t)b * NN * NN + (size_t)(m0 + arow) * NN + akc * 8;
    const f16* Xh_src = xTh + ((size_t)b * NC + arow) * NN + akc * 8;
    const f16* Xl_src = xTl + ((size_t)b * NC + arow) * NN + akc * 8;

#define D5STAGE(n0v, bufv) do { \
    *(f16x8*)&As_h[bufv][arow * ASTR + akc * 8] = *(const f16x8*)(Ah_src + (n0v)); \
    *(f16x8*)&As_l[bufv][arow * ASTR + akc * 8] = *(const f16x8*)(Al_src + (n0v)); \
    *(f16x8*)&Xs_h[bufv][arow * XSTR + akc * 8] = *(const f16x8*)(Xh_src + (n0v)); \
    *(f16x8*)&Xs_l[bufv][arow * XSTR + akc * 8] = *(const f16x8*)(Xl_src + (n0v)); \
} while (0)

#define D5MFMA(bufv) do { \
    _Pragma("unroll") \
    for (int ku = 0; ku < 2; ++ku) { \
        f16x8 Bh = *(const f16x8*)&Xs_h[bufv][(ch * 32 + l31) * XSTR + ku * 16 + g * 8]; \
        f16x8 Bl = *(const f16x8*)&Xs_l[bufv][(ch * 32 + l31) * XSTR + ku * 16 + g * 8]; \
        f16x8 Ah = *(const f16x8*)&As_h[bufv][(mh * 32 + l31) * ASTR + ku * 16 + g * 8]; \
        f16x8 Al = *(const f16x8*)&As_l[bufv][(mh * 32 + l31) * ASTR + ku * 16 + g * 8]; \
        acc = __builtin_amdgcn_mfma_f32_32x32x16_f16(Al, Bh, acc, 0, 0, 0); \
        acc = __builtin_amdgcn_mfma_f32_32x32x16_f16(Ah, Bl, acc, 0, 0, 0); \
        acc = __builtin_amdgcn_mfma_f32_32x32x16_f16(Ah, Bh, acc, 0, 0, 0); \
    } \
} while (0)

    f32x16 acc;
    #pragma unroll
    for (int r = 0; r < 16; ++r) acc[r] = 0.0f;

    D5STAGE(0, 0);
    __syncthreads();

    for (int s = 0; s < 32; ++s) {
        const int cur = s & 1;
        if (s + 1 < 32) D5STAGE((s + 1) * 32, cur ^ 1);
        D5MFMA(cur);
        __syncthreads();
    }
#undef D5STAGE
#undef D5MFMA

    const int colg = ch * 32 + l31;
    #pragma unroll
    for (int q = 0; q < 4; ++q) {
        float v[4];
        #pragma unroll
        for (int j = 0; j < 4; ++j) {
            int r = q * 4 + j;
            v[j] = lrelu(acc[r]);
        }
        const int mrow = m0 + mh * 32 + 8 * q + 4 * g;
        #pragma unroll
        for (int j = 0; j < 4; ++j)
            yout[((size_t)b * NN + mrow + j) * NC + colg] = v[j];
        if (writeT) {
            f16x4 ph, pl;
            #pragma unroll
            for (int j = 0; j < 4; ++j) {
                f16 h = (f16)v[j];
                ph[j] = h; pl[j] = (f16)(v[j] - (float)h);
            }
            *(f16x4*)&yTh[((size_t)b * NC + colg) * NN + mrow] = ph;
            *(f16x4*)&yTl[((size_t)b * NC + colg) * NN + mrow] = pl;
        }
    }
}

// ------- Fallback (fused MFMA diffuse, r4) -------
__global__ __launch_bounds__(256) void diffuse_mfma_kernel(
    const float* __restrict__ nv, const float* __restrict__ xin,
    float* __restrict__ yout)
{
    const int b = blockIdx.x;
    const int m0 = blockIdx.y * 128;
    const int t = threadIdx.x;
    const int l = t & 63;
    const int w = t >> 6;
    const int g = l >> 5;
    const int l31 = l & 31;

    __shared__ __align__(16) f16 nvA_h[128 * NVSTR], nvA_l[128 * NVSTR];
    __shared__ __align__(16) f16 nvB_h[2][32 * NVSTR], nvB_l[2][32 * NVSTR];
    __shared__ __align__(16) f16 xT_h[2][64 * XSTR], xT_l[2][64 * XSTR];
    __shared__ __align__(16) f16 S_h[128 * SSTR], S_l[128 * SSTR];

    {
        int row = t >> 1, e0 = (t & 1) * 8;
        const float* src = nv + ((size_t)b * NN + m0 + row) * NE + e0;
        #pragma unroll
        for (int q = 0; q < 4; ++q) {
            float v0 = src[2 * q], v1 = src[2 * q + 1];
            f16 h0 = (f16)v0, h1 = (f16)v1;
            f16 lo0 = (f16)(v0 - (float)h0), lo1 = (f16)(v1 - (float)h1);
            f16x2 ph; ph[0] = h0; ph[1] = h1;
            f16x2 pl; pl[0] = lo0; pl[1] = lo1;
            *(f16x2*)&nvA_h[row * NVSTR + e0 + 2 * q] = ph;
            *(f16x2*)&nvA_l[row * NVSTR + e0 + 2 * q] = pl;
        }
    }

#define STAGE(n0v, bufv) do { \
    if (t < 64) { \
        int nl_ = t >> 1, e0_ = (t & 1) * 8; \
        const float* s_ = nv + ((size_t)b * NN + (n0v) + nl_) * NE + e0_; \
        _Pragma("unroll") \
        for (int q = 0; q < 4; ++q) { \
            float v0 = s_[2 * q], v1 = s_[2 * q + 1]; \
            f16 h0 = (f16)v0, h1 = (f16)v1; \
            f16 lo0 = (f16)(v0 - (float)h0), lo1 = (f16)(v1 - (float)h1); \
            f16x2 ph; ph[0] = h0; ph[1] = h1; \
            f16x2 pl; pl[0] = lo0; pl[1] = lo1; \
            *(f16x2*)&nvB_h[bufv][nl_ * NVSTR + e0_ + 2 * q] = ph; \
            *(f16x2*)&nvB_l[bufv][nl_ * NVSTR + e0_ + 2 * q] = pl; \
        } \
    } \
    { \
        int k_ = t >> 3, c0_ = t & 7; \
        const float* s_ = xin + ((size_t)b * NN + (n0v) + k_) * NC + c0_; \
        _Pragma("unroll") \
        for (int i = 0; i < 8; ++i) { \
            float v = s_[8 * i]; \
            f16 h = (f16)v; f16 lo = (f16)(v - (float)h); \
            int c_ = c0_ + 8 * i; \
            xT_h[bufv][c_ * XSTR + k_] = h; \
            xT_l[bufv][c_ * XSTR + k_] = lo; \
        } \
    } \
} while (0)

    STAGE(0, 0);
    __syncthreads();

    f32x16 acc0, acc1;
    #pragma unroll
    for (int r = 0; r < 16; ++r) { acc0[r] = 0.0f; acc1[r] = 0.0f; }

    const int mh = w & 1;
    const int cc = w >> 1;

    for (int s = 0; s < 32; ++s) {
        const int cur = s & 1;
        {
            f16x8 Ah = *(const f16x8*)&nvA_h[(w * 32 + l31) * NVSTR + g * 8];
            f16x8 Al = *(const f16x8*)&nvA_l[(w * 32 + l31) * NVSTR + g * 8];
            f16x8 Bh = *(const f16x8*)&nvB_h[cur][l31 * NVSTR + g * 8];
            f16x8 Bl = *(const f16x8*)&nvB_l[cur][l31 * NVSTR + g * 8];
            f32x16 sa;
            #pragma unroll
            for (int r = 0; r < 16; ++r) sa[r] = 0.0f;
            sa = __builtin_amdgcn_mfma_f32_32x32x16_f16(Al, Bh, sa, 0, 0, 0);
            sa = __builtin_amdgcn_mfma_f32_32x32x16_f16(Ah, Bl, sa, 0, 0, 0);
            sa = __builtin_amdgcn_mfma_f32_32x32x16_f16(Ah, Bh, sa, 0, 0, 0);
            #pragma unroll
            for (int r = 0; r < 16; ++r) {
                float vv = fmaxf(sa[r], 0.0f);
                f16 h = (f16)vv; f16 lo = (f16)(vv - (float)h);
                int row = w * 32 + (r & 3) + 8 * (r >> 2) + 4 * g;
                S_h[row * SSTR + l31] = h;
                S_l[row * SSTR + l31] = lo;
            }
        }
        if (s + 1 < 32) STAGE((s + 1) * 32, cur ^ 1);
        __syncthreads();
        #pragma unroll
        for (int chh = 0; chh < 2; ++chh) {
            f16x8 Bh = *(const f16x8*)&xT_h[cur][(cc * 32 + l31) * XSTR + chh * 16 + g * 8];
            f16x8 Bl = *(const f16x8*)&xT_l[cur][(cc * 32 + l31) * XSTR + chh * 16 + g * 8];
            {
                int sr = (mh * 64 + l31) * SSTR + chh * 16 + g * 8;
                f16x8 Ah = *(const f16x8*)&S_h[sr];
                f16x8 Al = *(const f16x8*)&S_l[sr];
                acc0 = __builtin_amdgcn_mfma_f32_32x32x16_f16(Al, Bh, acc0, 0, 0, 0);
                acc0 = __builtin_amdgcn_mfma_f32_32x32x16_f16(Ah, Bl, acc0, 0, 0, 0);
                acc0 = __builtin_amdgcn_mfma_f32_32x32x16_f16(Ah, Bh, acc0, 0, 0, 0);
            }
            {
                int sr = (mh * 64 + 32 + l31) * SSTR + chh * 16 + g * 8;
                f16x8 Ah = *(const f16x8*)&S_h[sr];
                f16x8 Al = *(const f16x8*)&S_l[sr];
                acc1 = __builtin_amdgcn_mfma_f32_32x32x16_f16(Al, Bh, acc1, 0, 0, 0);
                acc1 = __builtin_amdgcn_mfma_f32_32x32x16_f16(Ah, Bl, acc1, 0, 0, 0);
                acc1 = __builtin_amdgcn_mfma_f32_32x32x16_f16(Ah, Bh, acc1, 0, 0, 0);
            }
        }
        __syncthreads();
    }
#undef STAGE

    const int colg = cc * 32 + l31;
    #pragma unroll
    for (int r = 0; r < 16; ++r) {
        int row0 = m0 + mh * 64 + (r & 3) + 8 * (r >> 2) + 4 * g;
        yout[((size_t)b * NN + row0) * NC + colg] = lrelu(acc0[r]);
        yout[((size_t)b * NN + row0 + 32) * NC + colg] = lrelu(acc1[r]);
    }
}

// ======= Attention pool, stage A: per-row scores (one wave per row) =======
__global__ __launch_bounds__(256) void scores_kernel(
    const float* __restrict__ x, const float* __restrict__ xs1, const float* __restrict__ xs2,
    const float* __restrict__ xb1, const float* __restrict__ xb2,
    const float* __restrict__ att_w, const float* __restrict__ att_b,
    float* __restrict__ sc)
{
    const int lane = threadIdx.x & 63;
    const int w = threadIdx.x >> 6;
    const int r = blockIdx.x * 4 + w;
    const int which = r >= NB * NN;
    const int rr = r - which * NB * NN;

    const float* p0 = which ? xs2 : x;
    const float* p1 = which ? xb1 : xs1;
    const float* p2 = which ? xb2 : xs2;

    size_t idx = (size_t)rr * NC + lane;
    float nf = (p0[idx] + p1[idx] + p2[idx]) * (1.0f / 3.0f);
    float v = nf * att_w[lane];
    #pragma unroll
    for (int off = 32; off > 0; off >>= 1) v += __shfl_xor(v, off);
    if (lane == 0) sc[r] = v + att_b[0];
}

// ======= Fallback softmax (mid tier) =======
__global__ __launch_bounds__(256) void softmax_kernel(float* __restrict__ sc)
{
    const int wb = blockIdx.x;
    const int t = threadIdx.x;
    const int lane = t & 63;
    const int w = t >> 6;
    float* p = sc + (size_t)wb * NN;

    __shared__ float red[4];
    float4 v = reinterpret_cast<const float4*>(p)[t];
    float m = fmaxf(fmaxf(v.x, v.y), fmaxf(v.z, v.w));
    #pragma unroll
    for (int off = 32; off > 0; off >>= 1) m = fmaxf(m, __shfl_xor(m, off));
    if (lane == 0) red[w] = m;
    __syncthreads();
    m = fmaxf(fmaxf(red[0], red[1]), fmaxf(red[2], red[3]));
    __syncthreads();
    v.x = expf(v.x - m); v.y = expf(v.y - m); v.z = expf(v.z - m); v.w = expf(v.w - m);
    float s = v.x + v.y + v.z + v.w;
    #pragma unroll
    for (int off = 32; off > 0; off >>= 1) s += __shfl_xor(s, off);
    if (lane == 0) red[w] = s;
    __syncthreads();
    const float inv = 1.0f / (red[0] + red[1] + red[2] + red[3]);
    v.x *= inv; v.y *= inv; v.z *= inv; v.w *= inv;
    reinterpret_cast<float4*>(p)[t] = v;
}

// ======= poolpart2: inline softmax stats (scb stays RAW scores) + weighted partials =======
__global__ __launch_bounds__(256) void poolpart2_kernel(
    const float* __restrict__ x, const float* __restrict__ xs1, const float* __restrict__ xs2,
    const float* __restrict__ xb1, const float* __restrict__ xb2,
    const float* __restrict__ sc, float* __restrict__ partial)
{
    const int chunk = blockIdx.x;
    const int b = blockIdx.y;
    const int which = blockIdx.z;
    const int t = threadIdx.x;
    const int lane = t & 63;
    const int w = t >> 6;

    const float* p0 = which ? xs2 : x;
    const float* p1 = which ? xb1 : xs1;
    const float* p2 = which ? xb2 : xs2;
    const float* srow = sc + ((size_t)which * NB + b) * NN;

    __shared__ float redm[4];
    __shared__ float reds[4];
    __shared__ float red[4][64];

    float4 v = reinterpret_cast<const float4*>(srow)[t];
    float m = fmaxf(fmaxf(v.x, v.y), fmaxf(v.z, v.w));
    #pragma unroll
    for (int off = 32; off > 0; off >>= 1) m = fmaxf(m, __shfl_xor(m, off));
    if (lane == 0) redm[w] = m;
    __syncthreads();
    m = fmaxf(fmaxf(redm[0], redm[1]), fmaxf(redm[2], redm[3]));
    float s = expf(v.x - m) + expf(v.y - m) + expf(v.z - m) + expf(v.w - m);
    #pragma unroll
    for (int off = 32; off > 0; off >>= 1) s += __shfl_xor(s, off);
    if (lane == 0) reds[w] = s;
    __syncthreads();
    const float inv = 1.0f / (reds[0] + reds[1] + reds[2] + reds[3]);

    const int n0 = chunk * 64;
    const size_t base = (size_t)b * NN;
    float acc = 0.0f;
    for (int j = w; j < 64; j += 4) {
        int n = n0 + j;
        float wgt = expf(srow[n] - m) * inv;
        size_t idx = (base + n) * NC + lane;
        float nf = (p0[idx] + p1[idx] + p2[idx]) * (1.0f / 3.0f);
        acc += nf * wgt;
    }
    red[w][lane] = acc;
    __syncthreads();
    if (w == 0) {
        float sv = red[0][lane] + red[1][lane] + red[2][lane] + red[3][lane];
        partial[(((size_t)which * NB + b) * 16 + chunk) * 64 + lane] = sv;
    }
}

// ======= Fallback poolpart (mid tier, expects normalized sc) =======
__global__ __launch_bounds__(256) void poolpart_kernel(
    const float* __restrict__ x, const float* __restrict__ xs1, const float* __restrict__ xs2,
    const float* __restrict__ xb1, const float* __restrict__ xb2,
    const float* __restrict__ sc, float* __restrict__ partial)
{
    const int chunk = blockIdx.x;
    const int b = blockIdx.y;
    const int which = blockIdx.z;
    const int lane = threadIdx.x & 63;
    const int w = threadIdx.x >> 6;

    const float* p0 = which ? xs2 : x;
    const float* p1 = which ? xb1 : xs1;
    const float* p2 = which ? xb2 : xs2;

    const int n0 = chunk * 64;
    const size_t base = (size_t)b * NN;
    float acc = 0.0f;
    for (int j = w; j < 64; j += 4) {
        int n = n0 + j;
        size_t idx = (base + n) * NC + lane;
        float nf = (p0[idx] + p1[idx] + p2[idx]) * (1.0f / 3.0f);
        acc += nf * sc[((size_t)which * NB + b) * NN + n];
    }
    __shared__ float red[4][64];
    red[w][lane] = acc;
    __syncthreads();
    if (w == 0) {
        float s = red[0][lane] + red[1][lane] + red[2][lane] + red[3][lane];
        partial[(((size_t)which * NB + b) * 16 + chunk) * 64 + lane] = s;
    }
}

// ======= Stage D: reduce partials + multiply by weights1 =======
__global__ __launch_bounds__(256) void poolfin_kernel(
    const float* __restrict__ partial, const float* __restrict__ w1,
    float* __restrict__ gf_out)
{
    const int wb = blockIdx.x;
    const int t = threadIdx.x;
    const int lane = t & 63;
    const int w = t >> 6;

    __shared__ float red[4][64];
    __shared__ float gfin[64];
    float acc = 0.0f;
    #pragma unroll
    for (int r = w; r < 16; r += 4)
        acc += partial[((size_t)wb * 16 + r) * 64 + lane];
    red[w][lane] = acc;
    __syncthreads();
    if (w == 0) gfin[lane] = red[0][lane] + red[1][lane] + red[2][lane] + red[3][lane];
    __syncthreads();
    if (w == 0) {
        float s = 0.0f;
        #pragma unroll
        for (int c = 0; c < 64; ++c) s += gfin[c] * w1[c * 64 + lane];
        gf_out[(size_t)wb * 64 + lane] = s;
    }
}

// ------- wbuild_both: one launch, z selects fwd/bwd pool and destination (f32 W) -------
__global__ __launch_bounds__(256) void wbuild_both_kernel(
    const float* __restrict__ emb1, const float* __restrict__ wpf,
    const float* __restrict__ wpb, float* __restrict__ Wf, float* __restrict__ Wb)
{
    const int ki = blockIdx.x;            // 0..191
    const int chunk = blockIdx.y;         // 0..3
    const int which = blockIdx.z;         // 0: fwd, 1: bwd
    const float* pool = which ? wpb : wpf;
    float* W = which ? Wb : Wf;
    const int t = threadIdx.x;
    const int o = t & 63;

    __shared__ float slab[16][64];
    __shared__ float eloc[256][16];

    for (int idx = t; idx < 1024; idx += 256)
        slab[idx >> 6][idx & 63] = pool[((size_t)(idx >> 6) * 192 + ki) * 64 + (idx & 63)];
    for (int idx = t; idx < 4096; idx += 256)
        eloc[idx >> 4][idx & 15] = emb1[((size_t)chunk * 256 + (idx >> 4)) * 16 + (idx & 15)];
    __syncthreads();
    for (int nl = t >> 6; nl < 256; nl += 4) {
        float s = 0.0f;
        #pragma unroll
        for (int e = 0; e < 16; ++e) s += eloc[nl][e] * slab[e][o];
        W[((size_t)(chunk * 256 + nl) * 192 + ki) * 64 + o] = s;
    }
}

// ------- apply_mfma: per node, GEMM [32b x 192ki x 64o] x 2 dirs via split-f16 MFMA -------
// 4 waves = (dir x o-tile). A = X states (LDS split f16), B = W rows loaded coalesced from
// global (f32) and split in-register.
__global__ __launch_bounds__(256) void apply_mfma_kernel(
    const float* __restrict__ Wf, const float* __restrict__ Wb,
    const float* __restrict__ emb1, const float* __restrict__ bias_pool,
    const float* __restrict__ x, const float* __restrict__ xs1, const float* __restrict__ xs2,
    const float* __restrict__ xb1, const float* __restrict__ xb2,
    const float* __restrict__ gf, const float* __restrict__ alpha, const float* __restrict__ beta,
    float* __restrict__ out)
{
    const int n = blockIdx.x;
    const int t = threadIdx.x;
    const int l = t & 63;
    const int g = l >> 5;
    const int l31 = l & 31;
    const int w = t >> 6;
    const int dir = w >> 1;   // 0: fwd (x,xs1,xs2), 1: bwd (xs2,xb1,xb2)
    const int ot  = w & 1;    // o-tile (32 cols)

    __shared__ __align__(16) f16 A5h[5][32 * A5STR], A5l[5][32 * A5STR];  // 45 KB
    __shared__ float e1s[16];

    if (t < 16) e1s[t] = emb1[n * 16 + t];

    const float* srcs[5] = {x, xs1, xs2, xb1, xb2};
    for (int idx = t; idx < 5 * 32 * 16; idx += 256) {
        int s = idx / (32 * 16);
        int rem = idx - s * (32 * 16);
        int b = rem >> 4, i4 = rem & 15;
        float4 v = *reinterpret_cast<const float4*>(srcs[s] + ((size_t)b * NN + n) * NC + i4 * 4);
        f16x4 ph, pl;
        ph[0] = (f16)v.x; pl[0] = (f16)(v.x - (float)ph[0]);
        ph[1] = (f16)v.y; pl[1] = (f16)(v.y - (float)ph[1]);
        ph[2] = (f16)v.z; pl[2] = (f16)(v.z - (float)ph[2]);
        ph[3] = (f16)v.w; pl[3] = (f16)(v.w - (float)ph[3]);
        *(f16x4*)&A5h[s][b * A5STR + i4 * 4] = ph;
        *(f16x4*)&A5l[s][b * A5STR + i4 * 4] = pl;
    }
    __syncthreads();

    const float* W = dir ? Wb : Wf;
    const float* wbase = W + (size_t)n * 192 * 64 + ot * 32 + l31;

    f32x16 acc;
    #pragma unroll
    for (int r = 0; r < 16; ++r) acc[r] = 0.0f;

    #pragma unroll 3
    for (int c = 0; c < 12; ++c) {        // 16-ki chunks
        const int ki0 = c * 16;
        const int s = dir * 2 + (ki0 >> 6);
        const int iloc = (ki0 & 63) + g * 8;
        f16x8 Ah = *(const f16x8*)&A5h[s][l31 * A5STR + iloc];
        f16x8 Al = *(const f16x8*)&A5l[s][l31 * A5STR + iloc];
        f16x8 Bh, Bl;
        #pragma unroll
        for (int j = 0; j < 8; ++j) {
            float wv = wbase[(size_t)(ki0 + g * 8 + j) * 64];
            f16 h = (f16)wv;
            Bh[j] = h; Bl[j] = (f16)(wv - (float)h);
        }
        acc = __builtin_amdgcn_mfma_f32_32x32x16_f16(Al, Bh, acc, 0, 0, 0);
        acc = __builtin_amdgcn_mfma_f32_32x32x16_f16(Ah, Bl, acc, 0, 0, 0);
        acc = __builtin_amdgcn_mfma_f32_32x32x16_f16(Ah, Bh, acc, 0, 0, 0);
    }

    __syncthreads();
    float* red = reinterpret_cast<float*>(&A5h[0][0]);   // [2][32][33]
    if (dir == 1) {
        #pragma unroll
        for (int r = 0; r < 16; ++r) {
            int crow = (r & 3) + 8 * (r >> 2) + 4 * g;
            red[(ot * 32 + crow) * 33 + l31] = acc[r];
        }
    }
    __syncthreads();
    if (dir == 0) {
        const int o = ot * 32 + l31;
        float bias_o = 0.0f;
        #pragma unroll
        for (int e = 0; e < 16; ++e) bias_o += e1s[e] * bias_pool[e * 64 + o];
        const float al = alpha[0], be = beta[0];
        #pragma unroll
        for (int r = 0; r < 16; ++r) {
            int b = (r & 3) + 8 * (r >> 2) + 4 * g;
            float gv = gf[(size_t)b * 64 + o] + gf[((size_t)NB + b) * 64 + o];
            out[((size_t)b * NN + n) * NC + o] =
                al * acc[r] + be * red[(ot * 32 + b) * 33 + l31] + bias_o + gv;
        }
    }
}

// ------- Fallback old wbuild/apply (ws-tier) -------
__global__ __launch_bounds__(256) void wbuild_kernel(
    const float* __restrict__ emb1, const float* __restrict__ pool,
    float* __restrict__ W)
{
    const int ki = blockIdx.x;
    const int chunk = blockIdx.y;
    const int t = threadIdx.x;
    const int o = t & 63;

    __shared__ float slab[16][64];
    __shared__ float eloc[256][16];

    for (int idx = t; idx < 1024; idx += 256)
        slab[idx >> 6][idx & 63] = pool[((size_t)(idx >> 6) * 192 + ki) * 64 + (idx & 63)];
    for (int idx = t; idx < 4096; idx += 256)
        eloc[idx >> 4][idx & 15] = emb1[((size_t)chunk * 256 + (idx >> 4)) * 16 + (idx & 15)];
    __syncthreads();
    for (int nl = t >> 6; nl < 256; nl += 4) {
        float s = 0.0f;
        #pragma unroll
        for (int e = 0; e < 16; ++e) s += eloc[nl][e] * slab[e][o];
        W[((size_t)(chunk * 256 + nl) * 192 + ki) * 64 + o] = s;
    }
}

__global__ __launch_bounds__(256) void apply_kernel(
    const float* __restrict__ W, const float* __restrict__ emb1,
    const float* __restrict__ bias_pool,
    const float* __restrict__ s0, const float* __restrict__ s1, const float* __restrict__ s2,
    const float* __restrict__ gf, const float* __restrict__ scale,
    float* __restrict__ out, int pass)
{
    const int n = blockIdx.x;
    const int t = threadIdx.x;
    const int o = t & 63;
    const int bg = t >> 6;

    __shared__ float Wn[192][64];
    __shared__ float Xs[3][32][64];
    __shared__ float e1s[16];

    if (t < 16) e1s[t] = emb1[n * 16 + t];
    {
        const float4* src = reinterpret_cast<const float4*>(W + (size_t)n * 192 * 64);
        float4* dst = reinterpret_cast<float4*>(&Wn[0][0]);
        #pragma unroll
        for (int r = 0; r < 12; ++r) dst[t + 256 * r] = src[t + 256 * r];
    }
    const float* srcs[3] = {s0, s1, s2};
    #pragma unroll
    for (int k = 0; k < 3; ++k) {
        const float* sp = srcs[k];
        #pragma unroll
        for (int r = 0; r < 2; ++r) {
            int idx = t + 256 * r;
            int b = idx >> 4, i4 = idx & 15;
            reinterpret_cast<float4*>(&Xs[k][b][0])[i4] =
                reinterpret_cast<const float4*>(sp + ((size_t)b * NN + n) * NC)[i4];
        }
    }
    __syncthreads();

    float acc[8] = {};
    #pragma unroll 4
    for (int ki = 0; ki < 192; ++ki) {
        float wv = Wn[ki][o];
        int k = ki >> 6, i = ki & 63;
        #pragma unroll
        for (int j = 0; j < 8; ++j) acc[j] += Xs[k][bg * 8 + j][i] * wv;
    }

    const float sc = scale[0];
    if (pass == 0) {
        float bias_o = 0.0f;
        #pragma unroll
        for (int e = 0; e < 16; ++e) bias_o += e1s[e] * bias_pool[e * 64 + o];
        #pragma unroll
        for (int j = 0; j < 8; ++j) {
            int b = bg * 8 + j;
            float g = gf[(size_t)b * 64 + o] + gf[((size_t)NB + b) * 64 + o];
            out[((size_t)b * NN + n) * NC + o] = sc * acc[j] + bias_o + g;
        }
    } else {
        #pragma unroll
        for (int j = 0; j < 8; ++j) {
            int b = bg * 8 + j;
            out[((size_t)b * NN + n) * NC + o] += sc * acc[j];
        }
    }
}

// ------- Fallback final kernel (ws too small) -------
__global__ __launch_bounds__(256) void final_kernel(
    const float* __restrict__ emb1,
    const float* __restrict__ wpf, const float* __restrict__ wpb,
    const float* __restrict__ bias_pool,
    const float* __restrict__ x, const float* __restrict__ xs1, const float* __restrict__ xs2,
    const float* __restrict__ xb1, const float* __restrict__ xb2,
    const float* __restrict__ gf, const float* __restrict__ alpha, const float* __restrict__ beta,
    float* __restrict__ out)
{
    const int n = blockIdx.x;
    const int t = threadIdx.x;
    const int o = t & 63;
    const int bg = t >> 6;

    __shared__ float Wk[64][64];
    __shared__ float xk[32][64];
    __shared__ float e1[16];
    if (t < 16) e1[t] = emb1[n * 16 + t];

    float acc[2][8];
    #pragma unroll
    for (int d = 0; d < 2; ++d)
        #pragma unroll
        for (int j = 0; j < 8; ++j) acc[d][j] = 0.0f;

    const float* srcs[2][3] = {{x, xs1, xs2}, {xs2, xb1, xb2}};

    #pragma unroll
    for (int dir = 0; dir < 2; ++dir) {
        const float* wp = dir ? wpb : wpf;
        #pragma unroll
        for (int k = 0; k < 3; ++k) {
            __syncthreads();
            for (int idx = t; idx < 4096; idx += 256) {
                int i = idx >> 6, oo = idx & 63;
                float s = 0.0f;
                #pragma unroll
                for (int e = 0; e < 16; ++e) s += e1[e] * wp[(((size_t)e * 3 + k) * 64 + i) * 64 + oo];
                Wk[i][oo] = s;
            }
            const float* src = srcs[dir][k];
            for (int idx = t; idx < 2048; idx += 256) {
                int bb = idx >> 6, ii = idx & 63;
                xk[bb][ii] = src[((size_t)bb * NN + n) * NC + ii];
            }
            __syncthreads();
            #pragma unroll
            for (int j = 0; j < 8; ++j) {
                int bb = bg * 8 + j;
                float s = 0.0f;
                #pragma unroll
                for (int i = 0; i < 64; i += 4) {
                    float4 xv = *reinterpret_cast<const float4*>(&xk[bb][i]);
                    s += xv.x * Wk[i][o] + xv.y * Wk[i + 1][o] + xv.z * Wk[i + 2][o] + xv.w * Wk[i + 3][o];
                }
                acc[dir][j] += s;
            }
        }
    }

    float bias_o = 0.0f;
    #pragma unroll
    for (int e = 0; e < 16; ++e) bias_o += e1[e] * bias_pool[e * 64 + o];
    const float al = alpha[0], be = beta[0];
    #pragma unroll
    for (int j = 0; j < 8; ++j) {
        int bb = bg * 8 + j;
        float g = gf[(size_t)bb * 64 + o] + gf[((size_t)NB + bb) * 64 + o];
        out[((size_t)bb * NN + n) * NC + o] = al * acc[0][j] + be * acc[1][j] + bias_o + g;
    }
}

// ------- Fallback attnpool (ws too small) -------
__global__ __launch_bounds__(256) void attnpool_kernel(
    const float* __restrict__ a0, const float* __restrict__ a1, const float* __restrict__ a2,
    const float* __restrict__ c0, const float* __restrict__ c1, const float* __restrict__ c2,
    const float* __restrict__ att_w, const float* __restrict__ att_b,
    const float* __restrict__ w1, float* __restrict__ gf_out)
{
    const int b = blockIdx.x;
    const int which = blockIdx.y;
    const float* p0 = which ? c0 : a0;
    const float* p1 = which ? c1 : a1;
    const float* p2 = which ? c2 : a2;
    const int t = threadIdx.x;
    const int lane = t & 63;
    const int w = t >> 6;

    __shared__ float sc[NN];
    __shared__ float red[4];
    __shared__ float gfp[4][64];
    __shared__ float gfin[64];

    const float aw = att_w[lane];
    const size_t base = (size_t)b * NN * NC;

    for (int n = w; n < NN; n += 4) {
        size_t idx = base + (size_t)n * NC + lane;
        float nf = (p0[idx] + p1[idx] + p2[idx]) * (1.0f / 3.0f);
        float v = nf * aw;
        #pragma unroll
        for (int off = 32; off > 0; off >>= 1) v += __shfl_xor(v, off);
        if (lane == 0) sc[n] = v + att_b[0];
    }
    __syncthreads();
    float m = -INFINITY;
    for (int i = t; i < NN; i += 256) m = fmaxf(m, sc[i]);
    #pragma unroll
    for (int off = 32; off > 0; off >>= 1) m = fmaxf(m, __shfl_xor(m, off));
    if (lane == 0) red[w] = m;
    __syncthreads();
    m = fmaxf(fmaxf(red[0], red[1]), fmaxf(red[2], red[3]));
    __syncthreads();
    float s = 0.0f;
    for (int i = t; i < NN; i += 256) { float e = expf(sc[i] - m); sc[i] = e; s += e; }
    #pragma unroll
    for (int off = 32; off > 0; off >>= 1) s += __shfl_xor(s, off);
    if (lane == 0) red[w] = s;
    __syncthreads();
    const float inv_denom = 1.0f / (red[0] + red[1] + red[2] + red[3]);

    float acc = 0.0f;
    for (int n = w; n < NN; n += 4) {
        size_t idx = base + (size_t)n * NC + lane;
        float nf = (p0[idx] + p1[idx] + p2[idx]) * (1.0f / 3.0f);
        acc += nf * sc[n];
    }
    gfp[w][lane] = acc;
    __syncthreads();
    if (w == 0) gfin[lane] = (gfp[0][lane] + gfp[1][lane] + gfp[2][lane] + gfp[3][lane]) * inv_denom;
    __syncthreads();
    if (w == 0) {
        float s2 = 0.0f;
        #pragma unroll
        for (int c = 0; c < 64; ++c) s2 += gfin[c] * w1[c * 64 + lane];
        gf_out[((size_t)which * NB + b) * 64 + lane] = s2;
    }
}

extern "C" void kernel_launch(void* const* d_in, const int* in_sizes, int n_in,
                              void* d_out, int out_size, void* d_ws, size_t ws_size,
                              hipStream_t stream)
{
    const float* x      = (const float*)d_in[0];
    const float* emb0   = (const float*)d_in[1];
    const float* emb1   = (const float*)d_in[2];
    const float* speed  = (const float*)d_in[5];
    const float* occupy = (const float*)d_in[6];
    const float* fw1 = (const float*)d_in[7];
    const float* fb1 = (const float*)d_in[8];
    const float* fw2 = (const float*)d_in[9];
    const float* fb2 = (const float*)d_in[10];
    const float* fw3 = (const float*)d_in[11];
    const float* fb3 = (const float*)d_in[12];
    const float* gw1 = (const float*)d_in[13];
    const float* gb1 = (const float*)d_in[14];
    const float* gw2 = (const float*)d_in[15];
    const float* gb2 = (const float*)d_in[16];
    const float* gw3 = (const float*)d_in[17];
    const float* gb3 = (const float*)d_in[18];
    const float* alpha = (const float*)d_in[19];
    const float* beta  = (const float*)d_in[20];
    const float* wpf = (const float*)d_in[21];
    const float* wpb = (const float*)d_in[22];
    const float* bias_pool = (const float*)d_in[23];
    const float* w1 = (const float*)d_in[24];
    const float* att_w = (const float*)d_in[25];
    const float* att_b = (const float*)d_in[26];
    float* out = (float*)d_out;

    float* ws = (float*)d_ws;
    float* nv  = ws;                                   // B*N*E
    float* xs1 = nv + (size_t)NB * NN * NE;            // B*N*C each
    float* xs2 = xs1 + (size_t)NB * NN * NC;
    float* xb1 = xs2 + (size_t)NB * NN * NC;
    float* xb2 = xb1 + (size_t)NB * NN * NC;
    float* gfb = xb2 + (size_t)NB * NN * NC;           // [2][B][64]
    float* scb = gfb + 4096;                           // [2][B][N]
    float* ppb = scb + (size_t)2 * NB * NN;            // [2][B][16][64]
    float* Wbuf = ppb + (size_t)2 * NB * 16 * 64;      // N*192*64
    f16* Sh = (f16*)(Wbuf + (size_t)NN * 192 * 64);    // B*N*N f16 planes
    f16* Sl = Sh + (size_t)NB * NN * NN;
    f16* T0h = Sl + (size_t)NB * NN * NN;              // B*C*N transposed split planes
    f16* T0l = T0h + (size_t)NB * NC * NN;
    f16* T1h = T0l + (size_t)NB * NC * NN;
    f16* T1l = T1h + (size_t)NB * NC * NN;
    float* WbufB = (float*)Sh;                         // aliased: S dead after last diffuse5

    const size_t base_elems = (size_t)NB * NN * NE + 4 * (size_t)NB * NN * NC + 4096;
    const size_t attn_elems = (size_t)2 * NB * NN + (size_t)2 * NB * 16 * 64;
    const size_t w_elems = (size_t)NN * 192 * 64;
    const size_t need_mid = (base_elems + attn_elems + w_elems) * sizeof(float);
    const size_t need_full = need_mid +
        ((size_t)2 * NB * NN * NN + (size_t)4 * NB * NC * NN) * sizeof(f16);

    if (ws_size >= need_full) {
        hipLaunchKernelGGL(nvxsplit_kernel, dim3(NB * 16 + NB * NN / 256), dim3(256), 0, stream,
                           x, emb0, speed, occupy, fw1, fb1, fw2, fb2, fw3, fb3,
                           gw1, gb1, gw2, gb2, gw3, gb3, nv, T0h, T0l);
        hipLaunchKernelGGL(sgen_fused_kernel, dim3(NB, NN / 128), dim3(512), 0, stream,
                           nv, T0h, T0l, Sh, Sl, xs1, T1h, T1l);
        dim3 gd5(NB, NN / 64);
        hipLaunchKernelGGL(diffuse5_kernel, gd5, dim3(256), 0, stream,
                           Sh, Sl, T1h, T1l, xs2, T0h, T0l, 1);
        hipLaunchKernelGGL(diffuse5_kernel, gd5, dim3(256), 0, stream,
                           Sh, Sl, T0h, T0l, xb1, T1h, T1l, 1);
        hipLaunchKernelGGL(diffuse5_kernel, gd5, dim3(256), 0, stream,
                           Sh, Sl, T1h, T1l, xb2, T0h, T0l, 0);
        // attention pool: scores (raw) -> poolpart2 (inline softmax) -> poolfin
        hipLaunchKernelGGL(scores_kernel, dim3(2 * NB * NN / 4), dim3(256), 0, stream,
                           x, xs1, xs2, xb1, xb2, att_w, att_b, scb);
        hipLaunchKernelGGL(poolpart2_kernel, dim3(16, NB, 2), dim3(256), 0, stream,
                           x, xs1, xs2, xb1, xb2, scb, ppb);
        hipLaunchKernelGGL(poolfin_kernel, dim3(2 * NB), dim3(256), 0, stream, ppb, w1, gfb);
        // final stage: one wbuild (both dirs; W_bwd aliased on dead S region), MFMA apply
        hipLaunchKernelGGL(wbuild_both_kernel, dim3(192, 4, 2), dim3(256), 0, stream,
                           emb1, wpf, wpb, Wbuf, WbufB);
        hipLaunchKernelGGL(apply_mfma_kernel, dim3(NN), dim3(256), 0, stream,
                           Wbuf, WbufB, emb1, bias_pool, x, xs1, xs2, xb1, xb2,
                           gfb, alpha, beta, out);
    } else if (ws_size >= need_mid) {
        hipLaunchKernelGGL(nv_kernel, dim3(NB * NN / 64), dim3(64), 0, stream,
                           x, emb0, speed, occupy, fw1, fb1, fw2, fb2, fw3, fb3,
                           gw1, gb1, gw2, gb2, gw3, gb3, nv);
        dim3 gd(NB, NN / 128);
        hipLaunchKernelGGL(diffuse_mfma_kernel, gd, dim3(256), 0, stream, nv, x, xs1);
        hipLaunchKernelGGL(diffuse_mfma_kernel, gd, dim3(256), 0, stream, nv, xs1, xs2);
        hipLaunchKernelGGL(diffuse_mfma_kernel, gd, dim3(256), 0, stream, nv, xs2, xb1);
        hipLaunchKernelGGL(diffuse_mfma_kernel, gd, dim3(256), 0, stream, nv, xb1, xb2);
        hipLaunchKernelGGL(scores_kernel, dim3(2 * NB * NN / 4), dim3(256), 0, stream,
                           x, xs1, xs2, xb1, xb2, att_w, att_b, scb);
        hipLaunchKernelGGL(softmax_kernel, dim3(2 * NB), dim3(256), 0, stream, scb);
        hipLaunchKernelGGL(poolpart_kernel, dim3(16, NB, 2), dim3(256), 0, stream,
                           x, xs1, xs2, xb1, xb2, scb, ppb);
        hipLaunchKernelGGL(poolfin_kernel, dim3(2 * NB), dim3(256), 0, stream, ppb, w1, gfb);
        hipLaunchKernelGGL(wbuild_kernel, dim3(192, 4), dim3(256), 0, stream, emb1, wpf, Wbuf);
        hipLaunchKernelGGL(apply_kernel, dim3(NN), dim3(256), 0, stream,
                           Wbuf, emb1, bias_pool, x, xs1, xs2, gfb, alpha, out, 0);
        hipLaunchKernelGGL(wbuild_kernel, dim3(192, 4), dim3(256), 0, stream, emb1, wpb, Wbuf);
        hipLaunchKernelGGL(apply_kernel, dim3(NN), dim3(256), 0, stream,
                           Wbuf, emb1, bias_pool, xs2, xb1, xb2, gfb, beta, out, 1);
    } else {
        hipLaunchKernelGGL(nv_kernel, dim3(NB * NN / 64), dim3(64), 0, stream,
                           x, emb0, speed, occupy, fw1, fb1, fw2, fb2, fw3, fb3,
                           gw1, gb1, gw2, gb2, gw3, gb3, nv);
        dim3 gd(NB, NN / 128);
        hipLaunchKernelGGL(diffuse_mfma_kernel, gd, dim3(256), 0, stream, nv, x, xs1);
        hipLaunchKernelGGL(diffuse_mfma_kernel, gd, dim3(256), 0, stream, nv, xs1, xs2);
        hipLaunchKernelGGL(diffuse_mfma_kernel, gd, dim3(256), 0, stream, nv, xs2, xb1);
        hipLaunchKernelGGL(diffuse_mfma_kernel, gd, dim3(256), 0, stream, nv, xb1, xb2);
        hipLaunchKernelGGL(attnpool_kernel, dim3(NB, 2), dim3(256), 0, stream,
                           x, xs1, xs2, xs2, xb1, xb2, att_w, att_b, w1, gfb);
        hipLaunchKernelGGL(final_kernel, dim3(NN), dim3(256), 0, stream,
                           emb1, wpf, wpb, bias_pool, x, xs1, xs2, xb1, xb2, gfb, alpha, beta, out);
    }
}